// Round 2
// baseline (648.301 us; speedup 1.0000x reference)
//
#include <hip/hip_runtime.h>

// ---------- types & helpers ----------
typedef float  f32x4 __attribute__((ext_vector_type(4)));
typedef short  short8 __attribute__((ext_vector_type(8)));

__device__ __forceinline__ unsigned short f2bf(float f) {
    unsigned u = __builtin_bit_cast(unsigned, f);
    unsigned r = u + 0x7FFFu + ((u >> 16) & 1u);
    return (unsigned short)(r >> 16);
}
__device__ __forceinline__ float bf2f(unsigned short b) {
    return __builtin_bit_cast(float, (unsigned)b << 16);
}

__device__ __forceinline__ f32x4 mfma16(short8 a, short8 b, f32x4 c) {
    return __builtin_amdgcn_mfma_f32_16x16x32_bf16(a, b, c, 0, 0, 0);
}

#define GLOAD16(gp, lp) \
    __builtin_amdgcn_global_load_lds((const __attribute__((address_space(1))) unsigned int*)(gp), \
                                     (__attribute__((address_space(3))) unsigned int*)(lp), 16, 0, 0)

// ---------- constants ----------
#define BT   4096
#define NTOK 16
#define DDIM 512
#define Y_ELEMS 33554432ULL        // BT*NTOK*DDIM
#define XS_STRIDE 516              // float row stride in LDS (bank-conflict-free 2-way)

// ---------- weight transpose fp32 [R][C] -> bf16 [C][R] ----------
__global__ __launch_bounds__(256) void transpose_kernel(const float* __restrict__ in,
                                                        unsigned short* __restrict__ out,
                                                        int R, int C) {
    __shared__ float tile[32][33];
    const int tx = threadIdx.x & 31, ty = threadIdx.x >> 5;
    const int c0 = blockIdx.x * 32, r0 = blockIdx.y * 32;
#pragma unroll
    for (int i = 0; i < 4; ++i)
        tile[ty + 8 * i][tx] = in[(size_t)(r0 + ty + 8 * i) * C + c0 + tx];
    __syncthreads();
#pragma unroll
    for (int i = 0; i < 4; ++i)
        out[(size_t)(c0 + ty + 8 * i) * R + r0 + tx] = f2bf(tile[tx][ty + 8 * i]);
}

// ---------- mask dtype detection: flag=1 -> byte layout, 0 -> int32 layout ----------
__global__ void detect_kernel(const unsigned char* __restrict__ m, int* __restrict__ flag) {
    __shared__ int any;
    if (threadIdx.x == 0) any = 0;
    __syncthreads();
    int loc = 0;
    for (int i = threadIdx.x; i < 4096; i += 256)
        if (i & 3) loc |= m[i];
    if (loc) atomicOr(&any, 1);
    __syncthreads();
    if (threadIdx.x == 0) *flag = any ? 1 : 0;
}

// ---------- stage 1 (pure fp32): scores, softmax, p@x, LN1 ----------
// Writes: attn (fp32, d_out region 1), h_bf16 (ws, GEMM1 input),
//         h_f32 (d_out y region, residual for GEMM2 epilogue).
__global__ __launch_bounds__(256) void stage1_kernel(
    const float* __restrict__ x,
    const unsigned char* __restrict__ mask_u8, const int* __restrict__ mask_i32,
    const int* __restrict__ flagp,
    const float* __restrict__ g1, const float* __restrict__ b1,
    float* __restrict__ attn_out, unsigned short* __restrict__ hbf,
    float* __restrict__ hf32) {
    __shared__ float xs[NTOK * XS_STRIDE];
    __shared__ float p_lds[256];

    const int b = blockIdx.x, t = threadIdx.x;
    const float* xb = x + (size_t)b * (NTOK * DDIM);

    // ---- load x tile (fp32, coalesced) ----
#pragma unroll
    for (int i = 0; i < 8; ++i) {
        int s = t + 256 * i;                 // f32x4 unit 0..2047
        int r = s >> 7, c4 = s & 127;
        f32x4 v = ((const f32x4*)xb)[s];
        *(f32x4*)(&xs[r * XS_STRIDE + c4 * 4]) = v;
    }
    __syncthreads();

    // ---- scores: thread t = r*16+c computes dot(x[r], x[c]) ----
    const int r = t >> 4, c = t & 15;
    {
        const f32x4* xr = (const f32x4*)(&xs[r * XS_STRIDE]);
        const f32x4* xc = (const f32x4*)(&xs[c * XS_STRIDE]);
        f32x4 d4 = {0.f, 0.f, 0.f, 0.f};
#pragma unroll 8
        for (int u = 0; u < 128; ++u) d4 += xr[u] * xc[u];
        float s_rc = (d4.x + d4.y + d4.z + d4.w) * 0.04419417382415922f; // 1/sqrt(512)

        const int flag = *flagp;
        size_t midx = (size_t)b * 256 + t;
        bool msk = flag ? (mask_u8[midx] != 0) : (mask_i32[midx] != 0);
        float sv = msk ? -1e30f : s_rc;
        float mx = sv;
        mx = fmaxf(mx, __shfl_xor(mx, 1, 16));
        mx = fmaxf(mx, __shfl_xor(mx, 2, 16));
        mx = fmaxf(mx, __shfl_xor(mx, 4, 16));
        mx = fmaxf(mx, __shfl_xor(mx, 8, 16));
        float e = msk ? 0.f : expf(sv - mx);
        float sum = e;
        sum += __shfl_xor(sum, 1, 16);
        sum += __shfl_xor(sum, 2, 16);
        sum += __shfl_xor(sum, 4, 16);
        sum += __shfl_xor(sum, 8, 16);
        float p = e / sum;
        p_lds[t] = p;
        attn_out[midx] = p;
    }
    __syncthreads();

    // ---- out = p @ x  (fp32), thread: row r2, f32x4 units u = tc + 16j ----
    const int r2 = t >> 4, tc = t & 15;
    f32x4 acc[8];
#pragma unroll
    for (int j = 0; j < 8; ++j) acc[j] = (f32x4){0.f, 0.f, 0.f, 0.f};
    for (int c2 = 0; c2 < 16; ++c2) {
        float pw = p_lds[r2 * 16 + c2];
        const f32x4* xrow = (const f32x4*)(&xs[c2 * XS_STRIDE]);
#pragma unroll
        for (int j = 0; j < 8; ++j) acc[j] += pw * xrow[tc + 16 * j];
    }

    // ---- h = LN(x + out), fp32 exact ----
    const f32x4* xme = (const f32x4*)(&xs[r2 * XS_STRIDE]);
    f32x4 vv[8];
    float s1 = 0.f, s2 = 0.f;
#pragma unroll
    for (int j = 0; j < 8; ++j) {
        f32x4 v = xme[tc + 16 * j] + acc[j];
        vv[j] = v;
        s1 += v.x + v.y + v.z + v.w;
        s2 += v.x * v.x + v.y * v.y + v.z * v.z + v.w * v.w;
    }
    s1 += __shfl_xor(s1, 1, 16); s2 += __shfl_xor(s2, 1, 16);
    s1 += __shfl_xor(s1, 2, 16); s2 += __shfl_xor(s2, 2, 16);
    s1 += __shfl_xor(s1, 4, 16); s2 += __shfl_xor(s2, 4, 16);
    s1 += __shfl_xor(s1, 8, 16); s2 += __shfl_xor(s2, 8, 16);
    float mu = s1 * (1.f / 512.f);
    float var = s2 * (1.f / 512.f) - mu * mu;
    float inv = rsqrtf(var + 1e-5f);

    const size_t rowbase = (size_t)(b * NTOK + r2) * DDIM;
    unsigned short* hrow = hbf + rowbase;
    float* frow = hf32 + rowbase;
#pragma unroll
    for (int j = 0; j < 8; ++j) {
        int u = tc + 16 * j;
        f32x4 gv = ((const f32x4*)g1)[u];
        f32x4 bv = ((const f32x4*)b1)[u];
        f32x4 o = (vv[j] - mu) * inv * gv + bv;
        *(f32x4*)(frow + u * 4) = o;
        uint2 pk;
        pk.x = (unsigned)f2bf(o.x) | ((unsigned)f2bf(o.y) << 16);
        pk.y = (unsigned)f2bf(o.z) | ((unsigned)f2bf(o.w) << 16);
        *(uint2*)(hrow + u * 4) = pk;
    }
}

// ---------- GEMM: C = A[128-tile][K] * B^T[128-tile][K] ; 2-phase, BK=32, 4 waves ----------
// FFN1: Cbf = bf16(relu(A*B + bias))           [t1]
// FFN2: Cf[idx] = A*B + bias + Cf[idx]         [z written over fp32 h in y region]
template <bool FFN1>
__global__ __launch_bounds__(256) void gemm_kernel(
    const unsigned short* __restrict__ A, const unsigned short* __restrict__ B,
    const float* __restrict__ bias, unsigned short* __restrict__ Cbf,
    float* Cf, long out_row0) {
    constexpr int K = FFN1 ? 512 : 2048;
    constexpr int NT = K / 32;
    constexpr int NLDC = FFN1 ? 2048 : 512;
    __shared__ unsigned short Al[2][128 * 32];
    __shared__ unsigned short Bl[2][128 * 32];

    const int t = threadIdx.x;
    const int n0 = blockIdx.x * 128;
    const int m0 = blockIdx.y * 128;
    const int l = t & 63, w = t >> 6, wm = w >> 1, wn = w & 1;

    f32x4 acc[4][4];
#pragma unroll
    for (int i = 0; i < 4; ++i)
#pragma unroll
        for (int j = 0; j < 4; ++j) acc[i][j] = (f32x4){0.f, 0.f, 0.f, 0.f};

    auto stage = [&](int kt, int bi) {
        const int k0 = kt * 32;
#pragma unroll
        for (int i = 0; i < 2; ++i) {
            int o = i * 4096 + t * 16;       // byte offset in tile, lane-linear within wave
            int row = o >> 6;
            int kb = (o & 63) >> 1;          // ushort offset within row
            GLOAD16(A + (size_t)(m0 + row) * K + k0 + kb, (char*)(&Al[bi][0]) + o);
            GLOAD16(B + (size_t)(n0 + row) * K + k0 + kb, (char*)(&Bl[bi][0]) + o);
        }
    };
    auto compute = [&](int bi) {
        short8 af[4], bfr[4];
#pragma unroll
        for (int mf = 0; mf < 4; ++mf)
            af[mf] = *(const short8*)(&Al[bi][(wm * 64 + mf * 16 + (l & 15)) * 32 + (l >> 4) * 8]);
#pragma unroll
        for (int nf = 0; nf < 4; ++nf)
            bfr[nf] = *(const short8*)(&Bl[bi][(wn * 64 + nf * 16 + (l & 15)) * 32 + (l >> 4) * 8]);
#pragma unroll
        for (int mf = 0; mf < 4; ++mf)
#pragma unroll
            for (int nf = 0; nf < 4; ++nf)
                acc[mf][nf] = mfma16(af[mf], bfr[nf], acc[mf][nf]);
    };

    stage(0, 0);
    __syncthreads();
    for (int kt = 0; kt < NT - 1; ++kt) {
        stage(kt + 1, (kt + 1) & 1);
        compute(kt & 1);
        __syncthreads();
    }
    compute((NT - 1) & 1);

    float bv[4];
#pragma unroll
    for (int nf = 0; nf < 4; ++nf) bv[nf] = bias[n0 + wn * 64 + nf * 16 + (l & 15)];

#pragma unroll
    for (int mf = 0; mf < 4; ++mf) {
#pragma unroll
        for (int q = 0; q < 4; ++q) {
            long row = m0 + wm * 64 + mf * 16 + (l >> 4) * 4 + q;
            if (FFN1) {
#pragma unroll
                for (int nf = 0; nf < 4; ++nf) {
                    int col = n0 + wn * 64 + nf * 16 + (l & 15);
                    float v = acc[mf][nf][q] + bv[nf];
                    Cbf[(size_t)row * NLDC + col] = f2bf(fmaxf(v, 0.f));
                }
            } else {
                long grow = out_row0 + row;
#pragma unroll
                for (int nf = 0; nf < 4; ++nf) {
                    int col = n0 + wn * 64 + nf * 16 + (l & 15);
                    size_t idx = (size_t)grow * 512 + col;
                    Cf[idx] = acc[mf][nf][q] + bv[nf] + Cf[idx];  // + fp32 h residual, in place
                }
            }
        }
    }
}

// ---------- LN2 in-place on d_out y region ----------
__global__ __launch_bounds__(256) void ln2_kernel(float* __restrict__ zy,
                                                  const float* __restrict__ g2,
                                                  const float* __restrict__ b2) {
    const int row = blockIdx.x * 4 + (threadIdx.x >> 6);
    const int l = threadIdx.x & 63;
    f32x4* rp = (f32x4*)(zy + (size_t)row * 512);
    f32x4 v0 = rp[l], v1 = rp[l + 64];
    float s = v0.x + v0.y + v0.z + v0.w + v1.x + v1.y + v1.z + v1.w;
    float s2 = v0.x * v0.x + v0.y * v0.y + v0.z * v0.z + v0.w * v0.w +
               v1.x * v1.x + v1.y * v1.y + v1.z * v1.z + v1.w * v1.w;
#pragma unroll
    for (int d = 1; d < 64; d <<= 1) {
        s += __shfl_xor(s, d, 64);
        s2 += __shfl_xor(s2, d, 64);
    }
    float mu = s * (1.f / 512.f);
    float var = s2 * (1.f / 512.f) - mu * mu;
    float inv = rsqrtf(var + 1e-5f);
    f32x4 ga = ((const f32x4*)g2)[l], gb = ((const f32x4*)g2)[l + 64];
    f32x4 ba = ((const f32x4*)b2)[l], bb = ((const f32x4*)b2)[l + 64];
    rp[l] = (v0 - mu) * inv * ga + ba;
    rp[l + 64] = (v1 - mu) * inv * gb + bb;
}

// ---------- host ----------
extern "C" void kernel_launch(void* const* d_in, const int* in_sizes, int n_in,
                              void* d_out, int out_size, void* d_ws, size_t ws_size,
                              hipStream_t stream) {
    const float* x = (const float*)d_in[0];
    const void* mask = d_in[1];
    const float* g1 = (const float*)d_in[2];
    const float* b1 = (const float*)d_in[3];
    const float* g2 = (const float*)d_in[4];
    const float* b2 = (const float*)d_in[5];
    const float* W1 = (const float*)d_in[6];
    const float* bW1 = (const float*)d_in[7];
    const float* W2 = (const float*)d_in[8];
    const float* bW2 = (const float*)d_in[9];

    float* y = (float*)d_out;                 // holds h_f32, then z, then y (in place)
    float* attn = y + Y_ELEMS;
    char* ws = (char*)d_ws;
    unsigned short* W1T = (unsigned short*)(ws);                 // 2 MiB  [2048][512]
    unsigned short* W2T = (unsigned short*)(ws + 2097152);       // 2 MiB  [512][2048]
    int* flag = (int*)(ws + 4194304);
    unsigned short* h = (unsigned short*)(ws + 4194560);         // 64 MiB [65536][512] bf16
    unsigned short* t1 = (unsigned short*)(ws + 71303424ULL);    // rest   [chunk][2048] bf16

    long cap_tiles = ((long)ws_size - 71303424L) / (128L * 2048L * 2L);
    if (cap_tiles < 1) cap_tiles = 1;
    if (cap_tiles > 512) cap_tiles = 512;

    transpose_kernel<<<dim3(64, 16), dim3(256), 0, stream>>>(W1, W1T, 512, 2048);
    transpose_kernel<<<dim3(16, 64), dim3(256), 0, stream>>>(W2, W2T, 2048, 512);
    detect_kernel<<<1, 256, 0, stream>>>((const unsigned char*)mask, flag);
    stage1_kernel<<<4096, 256, 0, stream>>>(x, (const unsigned char*)mask, (const int*)mask,
                                            flag, g1, b1, attn, h, y);
    for (long t0 = 0; t0 < 512; t0 += cap_tiles) {
        long mt = (512 - t0 < cap_tiles) ? (512 - t0) : cap_tiles;
        long row0 = t0 * 128;
        gemm_kernel<true><<<dim3(16, mt), dim3(256), 0, stream>>>(
            h + (size_t)row0 * 512, W1T, bW1, t1, nullptr, 0);
        gemm_kernel<false><<<dim3(4, mt), dim3(256), 0, stream>>>(
            t1, W2T, bW2, nullptr, y, row0);
    }
    ln2_kernel<<<16384, 256, 0, stream>>>(y, g2, b2);
}

// Round 4
// 445.745 us; speedup vs baseline: 1.4544x; 1.4544x over previous
//
#include <hip/hip_runtime.h>

// ---------- types & helpers ----------
typedef float  f32x4 __attribute__((ext_vector_type(4)));
typedef short  short8 __attribute__((ext_vector_type(8)));

__device__ __forceinline__ unsigned short f2bf(float f) {
    unsigned u = __builtin_bit_cast(unsigned, f);
    unsigned r = u + 0x7FFFu + ((u >> 16) & 1u);
    return (unsigned short)(r >> 16);
}
__device__ __forceinline__ float bf2f(unsigned short b) {
    return __builtin_bit_cast(float, (unsigned)b << 16);
}

__device__ __forceinline__ f32x4 mfma16(short8 a, short8 b, f32x4 c) {
    return __builtin_amdgcn_mfma_f32_16x16x32_bf16(a, b, c, 0, 0, 0);
}

#define GLOAD16(gp, lp) \
    __builtin_amdgcn_global_load_lds((const __attribute__((address_space(1))) unsigned int*)(gp), \
                                     (__attribute__((address_space(3))) unsigned int*)(lp), 16, 0, 0)

// ---------- constants ----------
#define BT   4096
#define NTOK 16
#define DDIM 512
#define Y_ELEMS 33554432ULL        // BT*NTOK*DDIM
#define XS_STRIDE 516

// ---------- weight transpose fp32 [R][C] -> bf16 [C][R] ----------
__global__ __launch_bounds__(256) void transpose_kernel(const float* __restrict__ in,
                                                        unsigned short* __restrict__ out,
                                                        int R, int C) {
    __shared__ float tile[32][33];
    const int tx = threadIdx.x & 31, ty = threadIdx.x >> 5;
    const int c0 = blockIdx.x * 32, r0 = blockIdx.y * 32;
#pragma unroll
    for (int i = 0; i < 4; ++i)
        tile[ty + 8 * i][tx] = in[(size_t)(r0 + ty + 8 * i) * C + c0 + tx];
    __syncthreads();
#pragma unroll
    for (int i = 0; i < 4; ++i)
        out[(size_t)(c0 + ty + 8 * i) * R + r0 + tx] = f2bf(tile[tx][ty + 8 * i]);
}

// ---------- mask dtype detection ----------
__global__ void detect_kernel(const unsigned char* __restrict__ m, int* __restrict__ flag) {
    __shared__ int any;
    if (threadIdx.x == 0) any = 0;
    __syncthreads();
    int loc = 0;
    for (int i = threadIdx.x; i < 4096; i += 256)
        if (i & 3) loc |= m[i];
    if (loc) atomicOr(&any, 1);
    __syncthreads();
    if (threadIdx.x == 0) *flag = any ? 1 : 0;
}

// ---------- stage 1 (pure fp32): scores, softmax, p@x, LN1 ----------
__global__ __launch_bounds__(256) void stage1_kernel(
    const float* __restrict__ x,
    const unsigned char* __restrict__ mask_u8, const int* __restrict__ mask_i32,
    const int* __restrict__ flagp,
    const float* __restrict__ g1, const float* __restrict__ b1,
    float* __restrict__ attn_out, unsigned short* __restrict__ hbf,
    float* __restrict__ hf32) {
    __shared__ float xs[NTOK * XS_STRIDE];
    __shared__ float p_lds[256];

    const int b = blockIdx.x, t = threadIdx.x;
    const float* xb = x + (size_t)b * (NTOK * DDIM);

#pragma unroll
    for (int i = 0; i < 8; ++i) {
        int s = t + 256 * i;
        int r = s >> 7, c4 = s & 127;
        f32x4 v = ((const f32x4*)xb)[s];
        *(f32x4*)(&xs[r * XS_STRIDE + c4 * 4]) = v;
    }
    __syncthreads();

    const int r = t >> 4, c = t & 15;
    {
        const f32x4* xr = (const f32x4*)(&xs[r * XS_STRIDE]);
        const f32x4* xc = (const f32x4*)(&xs[c * XS_STRIDE]);
        f32x4 d4 = {0.f, 0.f, 0.f, 0.f};
#pragma unroll 8
        for (int u = 0; u < 128; ++u) d4 += xr[u] * xc[u];
        float s_rc = (d4.x + d4.y + d4.z + d4.w) * 0.04419417382415922f;

        const int flag = *flagp;
        size_t midx = (size_t)b * 256 + t;
        bool msk = flag ? (mask_u8[midx] != 0) : (mask_i32[midx] != 0);
        float sv = msk ? -1e30f : s_rc;
        float mx = sv;
        mx = fmaxf(mx, __shfl_xor(mx, 1, 16));
        mx = fmaxf(mx, __shfl_xor(mx, 2, 16));
        mx = fmaxf(mx, __shfl_xor(mx, 4, 16));
        mx = fmaxf(mx, __shfl_xor(mx, 8, 16));
        float e = msk ? 0.f : expf(sv - mx);
        float sum = e;
        sum += __shfl_xor(sum, 1, 16);
        sum += __shfl_xor(sum, 2, 16);
        sum += __shfl_xor(sum, 4, 16);
        sum += __shfl_xor(sum, 8, 16);
        float p = e / sum;
        p_lds[t] = p;
        attn_out[midx] = p;
    }
    __syncthreads();

    const int r2 = t >> 4, tc = t & 15;
    f32x4 acc[8];
#pragma unroll
    for (int j = 0; j < 8; ++j) acc[j] = (f32x4){0.f, 0.f, 0.f, 0.f};
    for (int c2 = 0; c2 < 16; ++c2) {
        float pw = p_lds[r2 * 16 + c2];
        const f32x4* xrow = (const f32x4*)(&xs[c2 * XS_STRIDE]);
#pragma unroll
        for (int j = 0; j < 8; ++j) acc[j] += pw * xrow[tc + 16 * j];
    }

    const f32x4* xme = (const f32x4*)(&xs[r2 * XS_STRIDE]);
    f32x4 vv[8];
    float s1 = 0.f, s2 = 0.f;
#pragma unroll
    for (int j = 0; j < 8; ++j) {
        f32x4 v = xme[tc + 16 * j] + acc[j];
        vv[j] = v;
        s1 += v.x + v.y + v.z + v.w;
        s2 += v.x * v.x + v.y * v.y + v.z * v.z + v.w * v.w;
    }
    s1 += __shfl_xor(s1, 1, 16); s2 += __shfl_xor(s2, 1, 16);
    s1 += __shfl_xor(s1, 2, 16); s2 += __shfl_xor(s2, 2, 16);
    s1 += __shfl_xor(s1, 4, 16); s2 += __shfl_xor(s2, 4, 16);
    s1 += __shfl_xor(s1, 8, 16); s2 += __shfl_xor(s2, 8, 16);
    float mu = s1 * (1.f / 512.f);
    float var = s2 * (1.f / 512.f) - mu * mu;
    float inv = rsqrtf(var + 1e-5f);

    const size_t rowbase = (size_t)(b * NTOK + r2) * DDIM;
    unsigned short* hrow = hbf + rowbase;
    float* frow = hf32 + rowbase;
#pragma unroll
    for (int j = 0; j < 8; ++j) {
        int u = tc + 16 * j;
        f32x4 gv = ((const f32x4*)g1)[u];
        f32x4 bv = ((const f32x4*)b1)[u];
        f32x4 o = (vv[j] - mu) * inv * gv + bv;
        *(f32x4*)(frow + u * 4) = o;
        uint2 pk;
        pk.x = (unsigned)f2bf(o.x) | ((unsigned)f2bf(o.y) << 16);
        pk.y = (unsigned)f2bf(o.z) | ((unsigned)f2bf(o.w) << 16);
        *(uint2*)(hrow + u * 4) = pk;
    }
}

// ---------- 8-phase 256x256 GEMM (T1+T2+T3+T4+T5), BK=64, 8 waves ----------
// A: [rows][K] bf16 (pre-offset to chunk base). B: [N][K] bf16 weights.
// FFN1: Cbf = bf16(relu(A*B^T + bias)), chunk-local rows, N=2048.
// FFN2: Cf[g] = A*B^T + bias + Cf[g] (fp32 residual in place), N=512.

#define PH_READA(Al, Q) { short8 a00, a01, a10, a11; \
    a00 = *(const short8*)((Al) + aoffs[2*(Q)]   + kk2[0]); \
    a01 = *(const short8*)((Al) + aoffs[2*(Q)]   + kk2[1]); \
    a10 = *(const short8*)((Al) + aoffs[2*(Q)+1] + kk2[0]); \
    a11 = *(const short8*)((Al) + aoffs[2*(Q)+1] + kk2[1]);

#define PH_READB(Bl) \
    bb00 = *(const short8*)((Bl) + boffs[0] + kk2[0]); \
    bb01 = *(const short8*)((Bl) + boffs[0] + kk2[1]); \
    bb10 = *(const short8*)((Bl) + boffs[1] + kk2[0]); \
    bb11 = *(const short8*)((Bl) + boffs[1] + kk2[1]); \
    bb20 = *(const short8*)((Bl) + boffs[2] + kk2[0]); \
    bb21 = *(const short8*)((Bl) + boffs[2] + kk2[1]); \
    bb30 = *(const short8*)((Bl) + boffs[3] + kk2[0]); \
    bb31 = *(const short8*)((Bl) + boffs[3] + kk2[1]);

#define PH_MFMA(Q) \
    __builtin_amdgcn_s_barrier(); \
    asm volatile("s_waitcnt lgkmcnt(0)" ::: "memory"); \
    __builtin_amdgcn_sched_barrier(0); \
    __builtin_amdgcn_s_setprio(1); \
    acc[2*(Q)][0]   = mfma16(a00, bb00, acc[2*(Q)][0]); \
    acc[2*(Q)][0]   = mfma16(a01, bb01, acc[2*(Q)][0]); \
    acc[2*(Q)][1]   = mfma16(a00, bb10, acc[2*(Q)][1]); \
    acc[2*(Q)][1]   = mfma16(a01, bb11, acc[2*(Q)][1]); \
    acc[2*(Q)][2]   = mfma16(a00, bb20, acc[2*(Q)][2]); \
    acc[2*(Q)][2]   = mfma16(a01, bb21, acc[2*(Q)][2]); \
    acc[2*(Q)][3]   = mfma16(a00, bb30, acc[2*(Q)][3]); \
    acc[2*(Q)][3]   = mfma16(a01, bb31, acc[2*(Q)][3]); \
    acc[2*(Q)+1][0] = mfma16(a10, bb00, acc[2*(Q)+1][0]); \
    acc[2*(Q)+1][0] = mfma16(a11, bb01, acc[2*(Q)+1][0]); \
    acc[2*(Q)+1][1] = mfma16(a10, bb10, acc[2*(Q)+1][1]); \
    acc[2*(Q)+1][1] = mfma16(a11, bb11, acc[2*(Q)+1][1]); \
    acc[2*(Q)+1][2] = mfma16(a10, bb20, acc[2*(Q)+1][2]); \
    acc[2*(Q)+1][2] = mfma16(a11, bb21, acc[2*(Q)+1][2]); \
    acc[2*(Q)+1][3] = mfma16(a10, bb30, acc[2*(Q)+1][3]); \
    acc[2*(Q)+1][3] = mfma16(a11, bb31, acc[2*(Q)+1][3]); \
    __builtin_amdgcn_s_setprio(0);

#define PH_END  __builtin_amdgcn_s_barrier(); }

// One double-K-tile body: tiles u=2t (in buf0) and v=2t+1 (in buf1), 8 phases.
// MORE is a compile-time 0/1: whether tiles u2=2t+2, v2=2t+3 exist to prefetch.
#define GEMM_BODY(MORE) \
        PH_READA(A0lds, 0) PH_READB(B0lds) \
        stage(A, arow0, v, A1lds, 0); \
        stage(A, arow0, v, A1lds, 1); \
        PH_MFMA(0) PH_END \
        PH_READA(A0lds, 1) \
        if (MORE) stage(Bw, (size_t)n0, u2, B0lds, 0); \
        PH_MFMA(1) PH_END \
        PH_READA(A0lds, 2) \
        if (MORE) stage(Bw, (size_t)n0, u2, B0lds, 1); \
        PH_MFMA(2) PH_END \
        PH_READA(A0lds, 3) \
        PH_MFMA(3) \
        if (MORE) { asm volatile("s_waitcnt vmcnt(4)" ::: "memory"); } \
        else      { asm volatile("s_waitcnt vmcnt(0)" ::: "memory"); } \
        PH_END \
        PH_READA(A1lds, 0) PH_READB(B1lds) \
        if (MORE) stage(A, arow0, u2, A0lds, 0); \
        PH_MFMA(0) PH_END \
        PH_READA(A1lds, 1) \
        if (MORE) stage(A, arow0, u2, A0lds, 1); \
        PH_MFMA(1) PH_END \
        PH_READA(A1lds, 2) \
        if (MORE) stage(Bw, (size_t)n0, v2, B1lds, 0); \
        PH_MFMA(2) PH_END \
        PH_READA(A1lds, 3) \
        if (MORE) stage(Bw, (size_t)n0, v2, B1lds, 1); \
        PH_MFMA(3) \
        if (MORE) { asm volatile("s_waitcnt vmcnt(4)" ::: "memory"); } \
        PH_END

template <bool FFN1>
__global__ __launch_bounds__(512, 2) void gemm8_kernel(
    const unsigned short* __restrict__ A, const unsigned short* __restrict__ Bw,
    const float* __restrict__ bias, unsigned short* __restrict__ Cbf,
    float* Cf, long out_row0) {
    constexpr int K   = FFN1 ? 512 : 2048;
    constexpr int NT  = K / 64;            // K-tiles
    constexpr int NXT = FFN1 ? 8 : 2;      // N-tiles (N = 2048 / 512)
    constexpr int NC  = FFN1 ? 2048 : 512;

    extern __shared__ unsigned short lds[];
    unsigned short* A0lds = lds;            // [256][64] swizzled
    unsigned short* B0lds = lds + 16384;
    unsigned short* A1lds = lds + 32768;
    unsigned short* B1lds = lds + 49152;

    // m204 bijective XCD-chunk swizzle
    const int nwg = (int)gridDim.x;
    const int orig = (int)blockIdx.x;
    const int q8 = nwg >> 3, r8 = nwg & 7;
    const int xcd = orig & 7, idx = orig >> 3;
    const int w = (xcd < r8 ? xcd * (q8 + 1) : r8 * (q8 + 1) + (xcd - r8) * q8) + idx;
    const int mt_i = w / NXT, nt_i = w % NXT;
    const size_t arow0 = (size_t)mt_i * 256;
    const int n0 = nt_i * 256;

    const int tid = threadIdx.x;
    const int l = tid & 63, wv = tid >> 6;
    const int wm = wv >> 2, wn = wv & 3;       // 2 x 4 wave grid
    const int lr = l & 15, lq = l >> 4;

    // staging: chunk row = tid>>3 (0..63) within half, pre-swizzled k col (bytes^((row&7)<<4))
    const int srow = tid >> 3;
    const int skb  = ((((tid & 7) << 4) ^ ((srow & 7) << 4)) >> 1);

    // fragment read offsets (ushort units), swizzled
    const int sw = (lr & 7) << 4;
    int kk2[2];
    kk2[0] = ((lq * 16) ^ sw) >> 1;
    kk2[1] = ((64 + lq * 16) ^ sw) >> 1;
    int aoffs[8], boffs[4];
#pragma unroll
    for (int mf = 0; mf < 8; ++mf) aoffs[mf] = (wm * 128 + mf * 16 + lr) * 64;
#pragma unroll
    for (int nf = 0; nf < 4; ++nf) boffs[nf] = (wn * 64 + nf * 16 + lr) * 64;

    f32x4 acc[8][4];
#pragma unroll
    for (int i = 0; i < 8; ++i)
#pragma unroll
        for (int j = 0; j < 4; ++j) acc[i][j] = (f32x4){0.f, 0.f, 0.f, 0.f};

    short8 bb00, bb01, bb10, bb11, bb20, bb21, bb30, bb31;

    auto stage = [&](const unsigned short* gb, size_t rbase, int tile, unsigned short* dst, int half) {
        const unsigned short* g = gb + (rbase + (size_t)(half * 128 + srow)) * K + tile * 64 + skb;
        unsigned short* d = dst + half * 8192 + tid * 8;
        GLOAD16(g, d);
        GLOAD16(g + (size_t)64 * K, d + 4096);
    };

    // ---- prologue: B(0), A(0), B(1) staged; wait first 8, keep B(1) in flight ----
    stage(Bw, (size_t)n0, 0, B0lds, 0);
    stage(Bw, (size_t)n0, 0, B0lds, 1);
    stage(A,  arow0,      0, A0lds, 0);
    stage(A,  arow0,      0, A0lds, 1);
    stage(Bw, (size_t)n0, 1, B1lds, 0);
    stage(Bw, (size_t)n0, 1, B1lds, 1);
    asm volatile("s_waitcnt vmcnt(4)" ::: "memory");
    __builtin_amdgcn_s_barrier();

#pragma unroll 1
    for (int t = 0; t < NT / 2 - 1; ++t) {
        const int v = 2 * t + 1, u2 = 2 * t + 2, v2 = 2 * t + 3;
        GEMM_BODY(1)
    }
    {
        const int t = NT / 2 - 1;
        const int v = 2 * t + 1, u2 = 2 * t + 2, v2 = 2 * t + 3;
        (void)u2; (void)v2;
        GEMM_BODY(0)
    }

    // ---- epilogue ----
    float bv[4];
#pragma unroll
    for (int nf = 0; nf < 4; ++nf) bv[nf] = bias[n0 + wn * 64 + nf * 16 + lr];

#pragma unroll
    for (int mf = 0; mf < 8; ++mf) {
#pragma unroll
        for (int qq = 0; qq < 4; ++qq) {
            long row = (long)arow0 + wm * 128 + mf * 16 + lq * 4 + qq;
            if (FFN1) {
#pragma unroll
                for (int nf = 0; nf < 4; ++nf) {
                    int col = n0 + wn * 64 + nf * 16 + lr;
                    float vvv = acc[mf][nf][qq] + bv[nf];
                    Cbf[(size_t)row * NC + col] = f2bf(fmaxf(vvv, 0.f));
                }
            } else {
                long grow = out_row0 + row;
#pragma unroll
                for (int nf = 0; nf < 4; ++nf) {
                    int col = n0 + wn * 64 + nf * 16 + lr;
                    size_t gidx = (size_t)grow * 512 + col;
                    Cf[gidx] = acc[mf][nf][qq] + bv[nf] + Cf[gidx];
                }
            }
        }
    }
}

// ---------- LN2 in-place on d_out y region ----------
__global__ __launch_bounds__(256) void ln2_kernel(float* __restrict__ zy,
                                                  const float* __restrict__ g2,
                                                  const float* __restrict__ b2) {
    const int row = blockIdx.x * 4 + (threadIdx.x >> 6);
    const int l = threadIdx.x & 63;
    f32x4* rp = (f32x4*)(zy + (size_t)row * 512);
    f32x4 v0 = rp[l], v1 = rp[l + 64];
    float s = v0.x + v0.y + v0.z + v0.w + v1.x + v1.y + v1.z + v1.w;
    float s2 = v0.x * v0.x + v0.y * v0.y + v0.z * v0.z + v0.w * v0.w +
               v1.x * v1.x + v1.y * v1.y + v1.z * v1.z + v1.w * v1.w;
#pragma unroll
    for (int d = 1; d < 64; d <<= 1) {
        s += __shfl_xor(s, d, 64);
        s2 += __shfl_xor(s2, d, 64);
    }
    float mu = s * (1.f / 512.f);
    float var = s2 * (1.f / 512.f) - mu * mu;
    float inv = rsqrtf(var + 1e-5f);
    f32x4 ga = ((const f32x4*)g2)[l], gb = ((const f32x4*)g2)[l + 64];
    f32x4 ba = ((const f32x4*)b2)[l], bb = ((const f32x4*)b2)[l + 64];
    rp[l] = (v0 - mu) * inv * ga + ba;
    rp[l + 64] = (v1 - mu) * inv * gb + bb;
}

// ---------- host ----------
extern "C" void kernel_launch(void* const* d_in, const int* in_sizes, int n_in,
                              void* d_out, int out_size, void* d_ws, size_t ws_size,
                              hipStream_t stream) {
    const float* x = (const float*)d_in[0];
    const void* mask = d_in[1];
    const float* g1 = (const float*)d_in[2];
    const float* b1 = (const float*)d_in[3];
    const float* g2 = (const float*)d_in[4];
    const float* b2 = (const float*)d_in[5];
    const float* W1 = (const float*)d_in[6];
    const float* bW1 = (const float*)d_in[7];
    const float* W2 = (const float*)d_in[8];
    const float* bW2 = (const float*)d_in[9];

    float* y = (float*)d_out;                 // h_f32 -> z -> y (in place)
    float* attn = y + Y_ELEMS;
    char* ws = (char*)d_ws;
    unsigned short* W1T = (unsigned short*)(ws);                 // 2 MiB  [2048][512]
    unsigned short* W2T = (unsigned short*)(ws + 2097152);       // 2 MiB  [512][2048]
    int* flag = (int*)(ws + 4194304);
    unsigned short* h = (unsigned short*)(ws + 4194560);         // 64 MiB [65536][512] bf16
    unsigned short* t1 = (unsigned short*)(ws + 71303424ULL);    // [chunk*256][2048] bf16

    hipFuncSetAttribute((const void*)gemm8_kernel<true>,
                        hipFuncAttributeMaxDynamicSharedMemorySize, 131072);
    hipFuncSetAttribute((const void*)gemm8_kernel<false>,
                        hipFuncAttributeMaxDynamicSharedMemorySize, 131072);

    long cap256 = ((long)ws_size - 71303424L) / (256L * 2048L * 2L);
    if (cap256 < 1) cap256 = 1;
    if (cap256 > 256) cap256 = 256;

    transpose_kernel<<<dim3(64, 16), dim3(256), 0, stream>>>(W1, W1T, 512, 2048);
    transpose_kernel<<<dim3(16, 64), dim3(256), 0, stream>>>(W2, W2T, 2048, 512);
    detect_kernel<<<1, 256, 0, stream>>>((const unsigned char*)mask, flag);
    stage1_kernel<<<4096, 256, 0, stream>>>(x, (const unsigned char*)mask, (const int*)mask,
                                            flag, g1, b1, attn, h, y);
    for (long t0 = 0; t0 < 256; t0 += cap256) {
        long mt = (256 - t0 < cap256) ? (256 - t0) : cap256;
        long row0 = t0 * 256;
        gemm8_kernel<true><<<dim3((unsigned)(8 * mt)), 512, 131072, stream>>>(
            h + (size_t)row0 * 512, W1T, bW1, t1, nullptr, 0);
        gemm8_kernel<false><<<dim3((unsigned)(2 * mt)), 512, 131072, stream>>>(
            t1, W2T, bW2, nullptr, y, row0);
    }
    ln2_kernel<<<16384, 256, 0, stream>>>(y, g2, b2);
}

// Round 5
// 411.301 us; speedup vs baseline: 1.5762x; 1.0837x over previous
//
#include <hip/hip_runtime.h>

// ---------- types & helpers ----------
typedef float  f32x4 __attribute__((ext_vector_type(4)));
typedef short  short8 __attribute__((ext_vector_type(8)));

__device__ __forceinline__ unsigned short f2bf(float f) {
    unsigned u = __builtin_bit_cast(unsigned, f);
    unsigned r = u + 0x7FFFu + ((u >> 16) & 1u);
    return (unsigned short)(r >> 16);
}
__device__ __forceinline__ float bf2f(unsigned short b) {
    return __builtin_bit_cast(float, (unsigned)b << 16);
}

__device__ __forceinline__ f32x4 mfma16(short8 a, short8 b, f32x4 c) {
    return __builtin_amdgcn_mfma_f32_16x16x32_bf16(a, b, c, 0, 0, 0);
}

#define GLOAD16(gp, lp) \
    __builtin_amdgcn_global_load_lds((const __attribute__((address_space(1))) unsigned int*)(gp), \
                                     (__attribute__((address_space(3))) unsigned int*)(lp), 16, 0, 0)

// ---------- constants ----------
#define BT   4096
#define NTOK 16
#define DDIM 512
#define Y_ELEMS 33554432ULL        // BT*NTOK*DDIM
#define XS_STRIDE 516

// ---------- weight transpose fp32 [R][C] -> bf16 [C][R] ----------
__global__ __launch_bounds__(256) void transpose_kernel(const float* __restrict__ in,
                                                        unsigned short* __restrict__ out,
                                                        int R, int C) {
    __shared__ float tile[32][33];
    const int tx = threadIdx.x & 31, ty = threadIdx.x >> 5;
    const int c0 = blockIdx.x * 32, r0 = blockIdx.y * 32;
#pragma unroll
    for (int i = 0; i < 4; ++i)
        tile[ty + 8 * i][tx] = in[(size_t)(r0 + ty + 8 * i) * C + c0 + tx];
    __syncthreads();
#pragma unroll
    for (int i = 0; i < 4; ++i)
        out[(size_t)(c0 + ty + 8 * i) * R + r0 + tx] = f2bf(tile[tx][ty + 8 * i]);
}

// ---------- mask dtype detection ----------
__global__ void detect_kernel(const unsigned char* __restrict__ m, int* __restrict__ flag) {
    __shared__ int any;
    if (threadIdx.x == 0) any = 0;
    __syncthreads();
    int loc = 0;
    for (int i = threadIdx.x; i < 4096; i += 256)
        if (i & 3) loc |= m[i];
    if (loc) atomicOr(&any, 1);
    __syncthreads();
    if (threadIdx.x == 0) *flag = any ? 1 : 0;
}

// ---------- stage 1 (pure fp32): scores, softmax, p@x, LN1 -> h (bf16 only) ----------
__global__ __launch_bounds__(256) void stage1_kernel(
    const float* __restrict__ x,
    const unsigned char* __restrict__ mask_u8, const int* __restrict__ mask_i32,
    const int* __restrict__ flagp,
    const float* __restrict__ g1, const float* __restrict__ b1,
    float* __restrict__ attn_out, unsigned short* __restrict__ hbf) {
    __shared__ float xs[NTOK * XS_STRIDE];
    __shared__ float p_lds[256];

    const int b = blockIdx.x, t = threadIdx.x;
    const float* xb = x + (size_t)b * (NTOK * DDIM);

#pragma unroll
    for (int i = 0; i < 8; ++i) {
        int s = t + 256 * i;
        int r = s >> 7, c4 = s & 127;
        f32x4 v = ((const f32x4*)xb)[s];
        *(f32x4*)(&xs[r * XS_STRIDE + c4 * 4]) = v;
    }
    __syncthreads();

    const int r = t >> 4, c = t & 15;
    {
        const f32x4* xr = (const f32x4*)(&xs[r * XS_STRIDE]);
        const f32x4* xc = (const f32x4*)(&xs[c * XS_STRIDE]);
        f32x4 d4 = {0.f, 0.f, 0.f, 0.f};
#pragma unroll 8
        for (int u = 0; u < 128; ++u) d4 += xr[u] * xc[u];
        float s_rc = (d4.x + d4.y + d4.z + d4.w) * 0.04419417382415922f;

        const int flag = *flagp;
        size_t midx = (size_t)b * 256 + t;
        bool msk = flag ? (mask_u8[midx] != 0) : (mask_i32[midx] != 0);
        float sv = msk ? -1e30f : s_rc;
        float mx = sv;
        mx = fmaxf(mx, __shfl_xor(mx, 1, 16));
        mx = fmaxf(mx, __shfl_xor(mx, 2, 16));
        mx = fmaxf(mx, __shfl_xor(mx, 4, 16));
        mx = fmaxf(mx, __shfl_xor(mx, 8, 16));
        float e = msk ? 0.f : expf(sv - mx);
        float sum = e;
        sum += __shfl_xor(sum, 1, 16);
        sum += __shfl_xor(sum, 2, 16);
        sum += __shfl_xor(sum, 4, 16);
        sum += __shfl_xor(sum, 8, 16);
        float p = e / sum;
        p_lds[t] = p;
        attn_out[midx] = p;
    }
    __syncthreads();

    const int r2 = t >> 4, tc = t & 15;
    f32x4 acc[8];
#pragma unroll
    for (int j = 0; j < 8; ++j) acc[j] = (f32x4){0.f, 0.f, 0.f, 0.f};
    for (int c2 = 0; c2 < 16; ++c2) {
        float pw = p_lds[r2 * 16 + c2];
        const f32x4* xrow = (const f32x4*)(&xs[c2 * XS_STRIDE]);
#pragma unroll
        for (int j = 0; j < 8; ++j) acc[j] += pw * xrow[tc + 16 * j];
    }

    const f32x4* xme = (const f32x4*)(&xs[r2 * XS_STRIDE]);
    f32x4 vv[8];
    float s1 = 0.f, s2 = 0.f;
#pragma unroll
    for (int j = 0; j < 8; ++j) {
        f32x4 v = xme[tc + 16 * j] + acc[j];
        vv[j] = v;
        s1 += v.x + v.y + v.z + v.w;
        s2 += v.x * v.x + v.y * v.y + v.z * v.z + v.w * v.w;
    }
    s1 += __shfl_xor(s1, 1, 16); s2 += __shfl_xor(s2, 1, 16);
    s1 += __shfl_xor(s1, 2, 16); s2 += __shfl_xor(s2, 2, 16);
    s1 += __shfl_xor(s1, 4, 16); s2 += __shfl_xor(s2, 4, 16);
    s1 += __shfl_xor(s1, 8, 16); s2 += __shfl_xor(s2, 8, 16);
    float mu = s1 * (1.f / 512.f);
    float var = s2 * (1.f / 512.f) - mu * mu;
    float inv = rsqrtf(var + 1e-5f);

    unsigned short* hrow = hbf + (size_t)(b * NTOK + r2) * DDIM;
#pragma unroll
    for (int j = 0; j < 8; ++j) {
        int u = tc + 16 * j;
        f32x4 gv = ((const f32x4*)g1)[u];
        f32x4 bv = ((const f32x4*)b1)[u];
        f32x4 o = (vv[j] - mu) * inv * gv + bv;
        uint2 pk;
        pk.x = (unsigned)f2bf(o.x) | ((unsigned)f2bf(o.y) << 16);
        pk.y = (unsigned)f2bf(o.z) | ((unsigned)f2bf(o.w) << 16);
        *(uint2*)(hrow + u * 4) = pk;
    }
}

// ---------- FFN1: 8-phase 256x256 GEMM (unchanged from round 4, proven) ----------
#define PH_READA(Al, Q) { short8 a00, a01, a10, a11; \
    a00 = *(const short8*)((Al) + aoffs[2*(Q)]   + kk2[0]); \
    a01 = *(const short8*)((Al) + aoffs[2*(Q)]   + kk2[1]); \
    a10 = *(const short8*)((Al) + aoffs[2*(Q)+1] + kk2[0]); \
    a11 = *(const short8*)((Al) + aoffs[2*(Q)+1] + kk2[1]);

#define PH_READB(Bl) \
    bb00 = *(const short8*)((Bl) + boffs[0] + kk2[0]); \
    bb01 = *(const short8*)((Bl) + boffs[0] + kk2[1]); \
    bb10 = *(const short8*)((Bl) + boffs[1] + kk2[0]); \
    bb11 = *(const short8*)((Bl) + boffs[1] + kk2[1]); \
    bb20 = *(const short8*)((Bl) + boffs[2] + kk2[0]); \
    bb21 = *(const short8*)((Bl) + boffs[2] + kk2[1]); \
    bb30 = *(const short8*)((Bl) + boffs[3] + kk2[0]); \
    bb31 = *(const short8*)((Bl) + boffs[3] + kk2[1]);

#define PH_MFMA(Q) \
    __builtin_amdgcn_s_barrier(); \
    asm volatile("s_waitcnt lgkmcnt(0)" ::: "memory"); \
    __builtin_amdgcn_sched_barrier(0); \
    __builtin_amdgcn_s_setprio(1); \
    acc[2*(Q)][0]   = mfma16(a00, bb00, acc[2*(Q)][0]); \
    acc[2*(Q)][0]   = mfma16(a01, bb01, acc[2*(Q)][0]); \
    acc[2*(Q)][1]   = mfma16(a00, bb10, acc[2*(Q)][1]); \
    acc[2*(Q)][1]   = mfma16(a01, bb11, acc[2*(Q)][1]); \
    acc[2*(Q)][2]   = mfma16(a00, bb20, acc[2*(Q)][2]); \
    acc[2*(Q)][2]   = mfma16(a01, bb21, acc[2*(Q)][2]); \
    acc[2*(Q)][3]   = mfma16(a00, bb30, acc[2*(Q)][3]); \
    acc[2*(Q)][3]   = mfma16(a01, bb31, acc[2*(Q)][3]); \
    acc[2*(Q)+1][0] = mfma16(a10, bb00, acc[2*(Q)+1][0]); \
    acc[2*(Q)+1][0] = mfma16(a11, bb01, acc[2*(Q)+1][0]); \
    acc[2*(Q)+1][1] = mfma16(a10, bb10, acc[2*(Q)+1][1]); \
    acc[2*(Q)+1][1] = mfma16(a11, bb11, acc[2*(Q)+1][1]); \
    acc[2*(Q)+1][2] = mfma16(a10, bb20, acc[2*(Q)+1][2]); \
    acc[2*(Q)+1][2] = mfma16(a11, bb21, acc[2*(Q)+1][2]); \
    acc[2*(Q)+1][3] = mfma16(a10, bb30, acc[2*(Q)+1][3]); \
    acc[2*(Q)+1][3] = mfma16(a11, bb31, acc[2*(Q)+1][3]); \
    __builtin_amdgcn_s_setprio(0);

#define PH_END  __builtin_amdgcn_s_barrier(); }

#define GEMM_BODY(MORE) \
        PH_READA(A0lds, 0) PH_READB(B0lds) \
        stage(A, arow0, v, A1lds, 0); \
        stage(A, arow0, v, A1lds, 1); \
        PH_MFMA(0) PH_END \
        PH_READA(A0lds, 1) \
        if (MORE) stage(Bw, (size_t)n0, u2, B0lds, 0); \
        PH_MFMA(1) PH_END \
        PH_READA(A0lds, 2) \
        if (MORE) stage(Bw, (size_t)n0, u2, B0lds, 1); \
        PH_MFMA(2) PH_END \
        PH_READA(A0lds, 3) \
        PH_MFMA(3) \
        if (MORE) { asm volatile("s_waitcnt vmcnt(4)" ::: "memory"); } \
        else      { asm volatile("s_waitcnt vmcnt(0)" ::: "memory"); } \
        PH_END \
        PH_READA(A1lds, 0) PH_READB(B1lds) \
        if (MORE) stage(A, arow0, u2, A0lds, 0); \
        PH_MFMA(0) PH_END \
        PH_READA(A1lds, 1) \
        if (MORE) stage(A, arow0, u2, A0lds, 1); \
        PH_MFMA(1) PH_END \
        PH_READA(A1lds, 2) \
        if (MORE) stage(Bw, (size_t)n0, v2, B1lds, 0); \
        PH_MFMA(2) PH_END \
        PH_READA(A1lds, 3) \
        if (MORE) stage(Bw, (size_t)n0, v2, B1lds, 1); \
        PH_MFMA(3) \
        if (MORE) { asm volatile("s_waitcnt vmcnt(4)" ::: "memory"); } \
        PH_END

__global__ __launch_bounds__(512, 2) void gemm1_kernel(
    const unsigned short* __restrict__ A, const unsigned short* __restrict__ Bw,
    const float* __restrict__ bias, unsigned short* __restrict__ Cbf) {
    constexpr int K = 512;
    constexpr int NT = K / 64;
    constexpr int NXT = 8;                 // N = 2048
    constexpr int NC = 2048;

    extern __shared__ unsigned short lds[];
    unsigned short* A0lds = lds;
    unsigned short* B0lds = lds + 16384;
    unsigned short* A1lds = lds + 32768;
    unsigned short* B1lds = lds + 49152;

    const int nwg = (int)gridDim.x;
    const int orig = (int)blockIdx.x;
    const int q8 = nwg >> 3, r8 = nwg & 7;
    const int xcd = orig & 7, idx = orig >> 3;
    const int w = (xcd < r8 ? xcd * (q8 + 1) : r8 * (q8 + 1) + (xcd - r8) * q8) + idx;
    const int mt_i = w / NXT, nt_i = w % NXT;
    const size_t arow0 = (size_t)mt_i * 256;
    const int n0 = nt_i * 256;

    const int tid = threadIdx.x;
    const int l = tid & 63, wv = tid >> 6;
    const int wm = wv >> 2, wn = wv & 3;
    const int lr = l & 15, lq = l >> 4;

    const int srow = tid >> 3;
    const int skb = ((((tid & 7) << 4) ^ ((srow & 7) << 4)) >> 1);

    const int sw = (lr & 7) << 4;
    int kk2[2];
    kk2[0] = ((lq * 16) ^ sw) >> 1;
    kk2[1] = ((64 + lq * 16) ^ sw) >> 1;
    int aoffs[8], boffs[4];
#pragma unroll
    for (int mf = 0; mf < 8; ++mf) aoffs[mf] = (wm * 128 + mf * 16 + lr) * 64;
#pragma unroll
    for (int nf = 0; nf < 4; ++nf) boffs[nf] = (wn * 64 + nf * 16 + lr) * 64;

    f32x4 acc[8][4];
#pragma unroll
    for (int i = 0; i < 8; ++i)
#pragma unroll
        for (int j = 0; j < 4; ++j) acc[i][j] = (f32x4){0.f, 0.f, 0.f, 0.f};

    short8 bb00, bb01, bb10, bb11, bb20, bb21, bb30, bb31;

    auto stage = [&](const unsigned short* gb, size_t rbase, int tile, unsigned short* dst, int half) {
        const unsigned short* g = gb + (rbase + (size_t)(half * 128 + srow)) * K + tile * 64 + skb;
        unsigned short* d = dst + half * 8192 + tid * 8;
        GLOAD16(g, d);
        GLOAD16(g + (size_t)64 * K, d + 4096);
    };

    stage(Bw, (size_t)n0, 0, B0lds, 0);
    stage(Bw, (size_t)n0, 0, B0lds, 1);
    stage(A,  arow0,      0, A0lds, 0);
    stage(A,  arow0,      0, A0lds, 1);
    stage(Bw, (size_t)n0, 1, B1lds, 0);
    stage(Bw, (size_t)n0, 1, B1lds, 1);
    asm volatile("s_waitcnt vmcnt(4)" ::: "memory");
    __builtin_amdgcn_s_barrier();

#pragma unroll 1
    for (int t = 0; t < NT / 2 - 1; ++t) {
        const int v = 2 * t + 1, u2 = 2 * t + 2, v2 = 2 * t + 3;
        GEMM_BODY(1)
    }
    {
        const int t = NT / 2 - 1;
        const int v = 2 * t + 1, u2 = 2 * t + 2, v2 = 2 * t + 3;
        (void)u2; (void)v2;
        GEMM_BODY(0)
    }

    float bv[4];
#pragma unroll
    for (int nf = 0; nf < 4; ++nf) bv[nf] = bias[n0 + wn * 64 + nf * 16 + lr];

#pragma unroll
    for (int mf = 0; mf < 8; ++mf) {
#pragma unroll
        for (int qq = 0; qq < 4; ++qq) {
            long row = (long)arow0 + wm * 128 + mf * 16 + lq * 4 + qq;
#pragma unroll
            for (int nf = 0; nf < 4; ++nf) {
                int col = n0 + wn * 64 + nf * 16 + lr;
                float vvv = acc[mf][nf][qq] + bv[nf];
                Cbf[(size_t)row * NC + col] = f2bf(fmaxf(vvv, 0.f));
            }
        }
    }
}

// ---------- FFN2 + LN2 fused: y = LN(t1 @ W2^T + bW2 + h) ----------
// BM=128 rows (full 512-col rows per block), BK=64, 8 waves (wm=wv&1, wn=wv>>1).
// 8-phase counted-vmcnt schedule; phase Q = m-frag Q (all 16 B-frag reads at p0/p4).

#define Q2_READB(Bl) \
    _Pragma("unroll") \
    for (int nf = 0; nf < 8; ++nf) { \
        bb[2 * nf]     = *(const short8*)((Bl) + boffs2[nf] + kk2[0]); \
        bb[2 * nf + 1] = *(const short8*)((Bl) + boffs2[nf] + kk2[1]); \
    }

#define Q2_PH(Al, Q) { short8 a0_, a1_; \
    a0_ = *(const short8*)((Al) + aoffs2[Q] + kk2[0]); \
    a1_ = *(const short8*)((Al) + aoffs2[Q] + kk2[1]);

#define Q2_MFMA(Q) \
    __builtin_amdgcn_s_barrier(); \
    asm volatile("s_waitcnt lgkmcnt(0)" ::: "memory"); \
    __builtin_amdgcn_sched_barrier(0); \
    __builtin_amdgcn_s_setprio(1); \
    _Pragma("unroll") \
    for (int nf = 0; nf < 8; ++nf) { \
        acc[Q][nf] = mfma16(a0_, bb[2 * nf],     acc[Q][nf]); \
        acc[Q][nf] = mfma16(a1_, bb[2 * nf + 1], acc[Q][nf]); \
    } \
    __builtin_amdgcn_s_setprio(0);

#define Q2_END  __builtin_amdgcn_s_barrier(); }

#define BODY2(MORE) \
        Q2_READB(B0l) \
        Q2_PH(A0l, 0) stageA(v, A1l); Q2_MFMA(0) Q2_END \
        Q2_PH(A0l, 1) if (MORE) stageB(u2, B0l, 0); Q2_MFMA(1) Q2_END \
        Q2_PH(A0l, 2) if (MORE) stageB(u2, B0l, 1); Q2_MFMA(2) Q2_END \
        Q2_PH(A0l, 3) Q2_MFMA(3) \
        if (MORE) { asm volatile("s_waitcnt vmcnt(8)" ::: "memory"); } \
        else      { asm volatile("s_waitcnt vmcnt(0)" ::: "memory"); } \
        Q2_END \
        Q2_READB(B1l) \
        Q2_PH(A1l, 0) if (MORE) stageA(u2, A0l); Q2_MFMA(0) Q2_END \
        Q2_PH(A1l, 1) if (MORE) stageB(v2, B1l, 0); Q2_MFMA(1) Q2_END \
        Q2_PH(A1l, 2) if (MORE) stageB(v2, B1l, 1); Q2_MFMA(2) Q2_END \
        Q2_PH(A1l, 3) Q2_MFMA(3) \
        if (MORE) { asm volatile("s_waitcnt vmcnt(8)" ::: "memory"); } \
        Q2_END

__global__ __launch_bounds__(512, 2) void gemm2ln_kernel(
    const unsigned short* __restrict__ A,      // t1 chunk [rows][2048]
    const unsigned short* __restrict__ Bw,     // W2T [512][2048]
    const float* __restrict__ bias,            // bW2
    const unsigned short* __restrict__ hres,   // h bf16 (full, global rows)
    const float* __restrict__ g2, const float* __restrict__ b2,
    float* __restrict__ y, long out_row0) {
    constexpr int K = 2048;
    constexpr int NT = K / 64;                 // 32 K-tiles

    extern __shared__ unsigned short lds[];
    unsigned short* A0l = lds;                 // [128][64]
    unsigned short* A1l = lds + 8192;
    unsigned short* B0l = lds + 16384;         // [512][64]
    unsigned short* B1l = lds + 49152;

    // bijective XCD remap (pure M-tiles)
    const int nwg = (int)gridDim.x;
    const int orig = (int)blockIdx.x;
    const int q8 = nwg >> 3, r8 = nwg & 7;
    const int xcd = orig & 7, idx = orig >> 3;
    const int w = (xcd < r8 ? xcd * (q8 + 1) : r8 * (q8 + 1) + (xcd - r8) * q8) + idx;
    const size_t arow0 = (size_t)w * 128;

    const int tid = threadIdx.x;
    const int l = tid & 63, wv = tid >> 6;
    const int wm = wv & 1, wn = wv >> 1;       // 2 m-waves x 4 n-waves
    const int lr = l & 15, lq = l >> 4;

    const int srow = tid >> 3;
    const int skb = ((((tid & 7) << 4) ^ ((srow & 7) << 4)) >> 1);

    const int sw = (lr & 7) << 4;
    int kk2[2];
    kk2[0] = ((lq * 16) ^ sw) >> 1;
    kk2[1] = ((64 + lq * 16) ^ sw) >> 1;
    int aoffs2[4], boffs2[8];
#pragma unroll
    for (int mf = 0; mf < 4; ++mf) aoffs2[mf] = (wm * 64 + mf * 16 + lr) * 64;
#pragma unroll
    for (int nf = 0; nf < 8; ++nf) boffs2[nf] = (wn * 128 + nf * 16 + lr) * 64;

    f32x4 acc[4][8];
#pragma unroll
    for (int i = 0; i < 4; ++i)
#pragma unroll
        for (int j = 0; j < 8; ++j) acc[i][j] = (f32x4){0.f, 0.f, 0.f, 0.f};

    short8 bb[16];

    auto stageA = [&](int tile, unsigned short* dst) {
        const unsigned short* g = A + (arow0 + srow) * K + tile * 64 + skb;
        unsigned short* d = dst + tid * 8;
        GLOAD16(g, d);
        GLOAD16(g + (size_t)64 * K, d + 4096);
    };
    auto stageB = [&](int tile, unsigned short* dst, int half) {
        const unsigned short* g = Bw + (size_t)(half * 256 + srow) * K + tile * 64 + skb;
        unsigned short* d = dst + half * 16384 + tid * 8;
#pragma unroll
        for (int i = 0; i < 4; ++i)
            GLOAD16(g + (size_t)(64 * i) * K, d + 4096 * i);
    };

    // prologue: B(0) [8], A(0) [2], B(1) [8]; wait first 10 -> vmcnt(8)
    stageB(0, B0l, 0);
    stageB(0, B0l, 1);
    stageA(0, A0l);
    stageB(1, B1l, 0);
    stageB(1, B1l, 1);
    asm volatile("s_waitcnt vmcnt(8)" ::: "memory");
    __builtin_amdgcn_s_barrier();

#pragma unroll 1
    for (int t = 0; t < NT / 2 - 1; ++t) {
        const int v = 2 * t + 1, u2 = 2 * t + 2, v2 = 2 * t + 3;
        BODY2(1)
    }
    {
        const int t = NT / 2 - 1;
        const int v = 2 * t + 1, u2 = 2 * t + 2, v2 = 2 * t + 3;
        (void)u2; (void)v2;
        BODY2(0)
    }

    // ---- epilogue: bias + bf16-h residual, row LN across block, write y ----
    float* red = (float*)lds;                  // [sum:4x128][sq:4x128] floats
    float bv2[8], gv2[8], bb2[8];
#pragma unroll
    for (int nf = 0; nf < 8; ++nf) {
        int col = wn * 128 + nf * 16 + lr;
        bv2[nf] = bias[col];
        gv2[nf] = g2[col];
        bb2[nf] = b2[col];
    }

#pragma unroll
    for (int mf = 0; mf < 4; ++mf) {
#pragma unroll
        for (int qq = 0; qq < 4; ++qq) {
            int lrow = wm * 64 + mf * 16 + lq * 4 + qq;
            long grow = out_row0 + (long)arow0 + lrow;
            const unsigned short* hr = hres + (size_t)grow * 512 + wn * 128 + lr;
            float s = 0.f, s2 = 0.f;
#pragma unroll
            for (int nf = 0; nf < 8; ++nf) {
                float z = acc[mf][nf][qq] + bv2[nf] + bf2f(hr[nf * 16]);
                acc[mf][nf][qq] = z;
                s += z;
                s2 += z * z;
            }
            s += __shfl_xor(s, 1, 16); s2 += __shfl_xor(s2, 1, 16);
            s += __shfl_xor(s, 2, 16); s2 += __shfl_xor(s2, 2, 16);
            s += __shfl_xor(s, 4, 16); s2 += __shfl_xor(s2, 4, 16);
            s += __shfl_xor(s, 8, 16); s2 += __shfl_xor(s2, 8, 16);
            if (lr == 0) {
                red[wn * 128 + lrow] = s;
                red[512 + wn * 128 + lrow] = s2;
            }
        }
    }
    __syncthreads();

#pragma unroll
    for (int mf = 0; mf < 4; ++mf) {
#pragma unroll
        for (int qq = 0; qq < 4; ++qq) {
            int lrow = wm * 64 + mf * 16 + lq * 4 + qq;
            long grow = out_row0 + (long)arow0 + lrow;
            float s = red[lrow] + red[128 + lrow] + red[256 + lrow] + red[384 + lrow];
            float s2 = red[512 + lrow] + red[640 + lrow] + red[768 + lrow] + red[896 + lrow];
            float mu = s * (1.f / 512.f);
            float var = s2 * (1.f / 512.f) - mu * mu;
            float inv = rsqrtf(var + 1e-5f);
            float* yr = y + (size_t)grow * 512 + wn * 128 + lr;
#pragma unroll
            for (int nf = 0; nf < 8; ++nf)
                yr[nf * 16] = (acc[mf][nf][qq] - mu) * inv * gv2[nf] + bb2[nf];
        }
    }
}

// ---------- host ----------
extern "C" void kernel_launch(void* const* d_in, const int* in_sizes, int n_in,
                              void* d_out, int out_size, void* d_ws, size_t ws_size,
                              hipStream_t stream) {
    const float* x = (const float*)d_in[0];
    const void* mask = d_in[1];
    const float* g1 = (const float*)d_in[2];
    const float* b1 = (const float*)d_in[3];
    const float* g2 = (const float*)d_in[4];
    const float* b2 = (const float*)d_in[5];
    const float* W1 = (const float*)d_in[6];
    const float* bW1 = (const float*)d_in[7];
    const float* W2 = (const float*)d_in[8];
    const float* bW2 = (const float*)d_in[9];

    float* y = (float*)d_out;
    float* attn = y + Y_ELEMS;
    char* ws = (char*)d_ws;
    unsigned short* W1T = (unsigned short*)(ws);                 // 2 MiB  [2048][512]
    unsigned short* W2T = (unsigned short*)(ws + 2097152);       // 2 MiB  [512][2048]
    int* flag = (int*)(ws + 4194304);
    unsigned short* h = (unsigned short*)(ws + 4194560);         // 64 MiB [65536][512] bf16
    unsigned short* t1 = (unsigned short*)(ws + 71303424ULL);    // [chunk*256][2048] bf16

    hipFuncSetAttribute((const void*)gemm1_kernel,
                        hipFuncAttributeMaxDynamicSharedMemorySize, 131072);
    hipFuncSetAttribute((const void*)gemm2ln_kernel,
                        hipFuncAttributeMaxDynamicSharedMemorySize, 163840);

    long cap256 = ((long)ws_size - 71303424L) / (256L * 2048L * 2L);
    if (cap256 < 1) cap256 = 1;
    if (cap256 > 256) cap256 = 256;

    transpose_kernel<<<dim3(64, 16), dim3(256), 0, stream>>>(W1, W1T, 512, 2048);
    transpose_kernel<<<dim3(16, 64), dim3(256), 0, stream>>>(W2, W2T, 2048, 512);
    detect_kernel<<<1, 256, 0, stream>>>((const unsigned char*)mask, flag);
    stage1_kernel<<<4096, 256, 0, stream>>>(x, (const unsigned char*)mask, (const int*)mask,
                                            flag, g1, b1, attn, h);
    for (long t0 = 0; t0 < 256; t0 += cap256) {
        long mt = (256 - t0 < cap256) ? (256 - t0) : cap256;
        long row0 = t0 * 256;
        gemm1_kernel<<<dim3((unsigned)(8 * mt)), 512, 131072, stream>>>(
            h + (size_t)row0 * 512, W1T, bW1, t1);
        gemm2ln_kernel<<<dim3((unsigned)(2 * mt)), 512, 163840, stream>>>(
            t1, W2T, bW2, h, g2, b2, y, row0);
    }
}

// Round 7
// 406.062 us; speedup vs baseline: 1.5966x; 1.0129x over previous
//
#include <hip/hip_runtime.h>

// ---------- types & helpers ----------
typedef float  f32x4 __attribute__((ext_vector_type(4)));
typedef short  short8 __attribute__((ext_vector_type(8)));

__device__ __forceinline__ unsigned short f2bf(float f) {
    unsigned u = __builtin_bit_cast(unsigned, f);
    unsigned r = u + 0x7FFFu + ((u >> 16) & 1u);
    return (unsigned short)(r >> 16);
}
__device__ __forceinline__ float bf2f(unsigned short b) {
    return __builtin_bit_cast(float, (unsigned)b << 16);
}

__device__ __forceinline__ f32x4 mfma16(short8 a, short8 b, f32x4 c) {
    return __builtin_amdgcn_mfma_f32_16x16x32_bf16(a, b, c, 0, 0, 0);
}

#define GLOAD16(gp, lp) \
    __builtin_amdgcn_global_load_lds((const __attribute__((address_space(1))) unsigned int*)(gp), \
                                     (__attribute__((address_space(3))) unsigned int*)(lp), 16, 0, 0)

// ---------- constants ----------
#define BT   4096
#define NTOK 16
#define DDIM 512
#define Y_ELEMS 33554432ULL        // BT*NTOK*DDIM
#define XS_STRIDE 516

// ---------- weight transpose fp32 [R][C] -> bf16 [C][R] ----------
__global__ __launch_bounds__(256) void transpose_kernel(const float* __restrict__ in,
                                                        unsigned short* __restrict__ out,
                                                        int R, int C) {
    __shared__ float tile[32][33];
    const int tx = threadIdx.x & 31, ty = threadIdx.x >> 5;
    const int c0 = blockIdx.x * 32, r0 = blockIdx.y * 32;
#pragma unroll
    for (int i = 0; i < 4; ++i)
        tile[ty + 8 * i][tx] = in[(size_t)(r0 + ty + 8 * i) * C + c0 + tx];
    __syncthreads();
#pragma unroll
    for (int i = 0; i < 4; ++i)
        out[(size_t)(c0 + ty + 8 * i) * R + r0 + tx] = f2bf(tile[tx][ty + 8 * i]);
}

// ---------- mask dtype detection ----------
__global__ void detect_kernel(const unsigned char* __restrict__ m, int* __restrict__ flag) {
    __shared__ int any;
    if (threadIdx.x == 0) any = 0;
    __syncthreads();
    int loc = 0;
    for (int i = threadIdx.x; i < 4096; i += 256)
        if (i & 3) loc |= m[i];
    if (loc) atomicOr(&any, 1);
    __syncthreads();
    if (threadIdx.x == 0) *flag = any ? 1 : 0;
}

// ---------- stage 1 (pure fp32): scores, softmax, p@x, LN1 -> h (bf16 only) ----------
__global__ __launch_bounds__(256) void stage1_kernel(
    const float* __restrict__ x,
    const unsigned char* __restrict__ mask_u8, const int* __restrict__ mask_i32,
    const int* __restrict__ flagp,
    const float* __restrict__ g1, const float* __restrict__ b1,
    float* __restrict__ attn_out, unsigned short* __restrict__ hbf) {
    __shared__ float xs[NTOK * XS_STRIDE];
    __shared__ float p_lds[256];

    const int b = blockIdx.x, t = threadIdx.x;
    const float* xb = x + (size_t)b * (NTOK * DDIM);

#pragma unroll
    for (int i = 0; i < 8; ++i) {
        int s = t + 256 * i;
        int r = s >> 7, c4 = s & 127;
        f32x4 v = ((const f32x4*)xb)[s];
        *(f32x4*)(&xs[r * XS_STRIDE + c4 * 4]) = v;
    }
    __syncthreads();

    const int r = t >> 4, c = t & 15;
    {
        const f32x4* xr = (const f32x4*)(&xs[r * XS_STRIDE]);
        const f32x4* xc = (const f32x4*)(&xs[c * XS_STRIDE]);
        f32x4 d4 = {0.f, 0.f, 0.f, 0.f};
#pragma unroll 8
        for (int u = 0; u < 128; ++u) d4 += xr[u] * xc[u];
        float s_rc = (d4.x + d4.y + d4.z + d4.w) * 0.04419417382415922f;

        const int flag = *flagp;
        size_t midx = (size_t)b * 256 + t;
        bool msk = flag ? (mask_u8[midx] != 0) : (mask_i32[midx] != 0);
        float sv = msk ? -1e30f : s_rc;
        float mx = sv;
        mx = fmaxf(mx, __shfl_xor(mx, 1, 16));
        mx = fmaxf(mx, __shfl_xor(mx, 2, 16));
        mx = fmaxf(mx, __shfl_xor(mx, 4, 16));
        mx = fmaxf(mx, __shfl_xor(mx, 8, 16));
        float e = msk ? 0.f : expf(sv - mx);
        float sum = e;
        sum += __shfl_xor(sum, 1, 16);
        sum += __shfl_xor(sum, 2, 16);
        sum += __shfl_xor(sum, 4, 16);
        sum += __shfl_xor(sum, 8, 16);
        float p = e / sum;
        p_lds[t] = p;
        attn_out[midx] = p;
    }
    __syncthreads();

    const int r2 = t >> 4, tc = t & 15;
    f32x4 acc[8];
#pragma unroll
    for (int j = 0; j < 8; ++j) acc[j] = (f32x4){0.f, 0.f, 0.f, 0.f};
    for (int c2 = 0; c2 < 16; ++c2) {
        float pw = p_lds[r2 * 16 + c2];
        const f32x4* xrow = (const f32x4*)(&xs[c2 * XS_STRIDE]);
#pragma unroll
        for (int j = 0; j < 8; ++j) acc[j] += pw * xrow[tc + 16 * j];
    }

    const f32x4* xme = (const f32x4*)(&xs[r2 * XS_STRIDE]);
    f32x4 vv[8];
    float s1 = 0.f, s2 = 0.f;
#pragma unroll
    for (int j = 0; j < 8; ++j) {
        f32x4 v = xme[tc + 16 * j] + acc[j];
        vv[j] = v;
        s1 += v.x + v.y + v.z + v.w;
        s2 += v.x * v.x + v.y * v.y + v.z * v.z + v.w * v.w;
    }
    s1 += __shfl_xor(s1, 1, 16); s2 += __shfl_xor(s2, 1, 16);
    s1 += __shfl_xor(s1, 2, 16); s2 += __shfl_xor(s2, 2, 16);
    s1 += __shfl_xor(s1, 4, 16); s2 += __shfl_xor(s2, 4, 16);
    s1 += __shfl_xor(s1, 8, 16); s2 += __shfl_xor(s2, 8, 16);
    float mu = s1 * (1.f / 512.f);
    float var = s2 * (1.f / 512.f) - mu * mu;
    float inv = rsqrtf(var + 1e-5f);

    unsigned short* hrow = hbf + (size_t)(b * NTOK + r2) * DDIM;
#pragma unroll
    for (int j = 0; j < 8; ++j) {
        int u = tc + 16 * j;
        f32x4 gv = ((const f32x4*)g1)[u];
        f32x4 bv = ((const f32x4*)b1)[u];
        f32x4 o = (vv[j] - mu) * inv * gv + bv;
        uint2 pk;
        pk.x = (unsigned)f2bf(o.x) | ((unsigned)f2bf(o.y) << 16);
        pk.y = (unsigned)f2bf(o.z) | ((unsigned)f2bf(o.w) << 16);
        *(uint2*)(hrow + u * 4) = pk;
    }
}

// ---------- FFN1: 8-phase 256x256 GEMM, ONE barrier per phase ----------
#define PH_READA(Al, Q) { short8 a00, a01, a10, a11; \
    a00 = *(const short8*)((Al) + aoffs[2*(Q)]   + kk2[0]); \
    a01 = *(const short8*)((Al) + aoffs[2*(Q)]   + kk2[1]); \
    a10 = *(const short8*)((Al) + aoffs[2*(Q)+1] + kk2[0]); \
    a11 = *(const short8*)((Al) + aoffs[2*(Q)+1] + kk2[1]);

#define PH_READB(Bl) \
    bb00 = *(const short8*)((Bl) + boffs[0] + kk2[0]); \
    bb01 = *(const short8*)((Bl) + boffs[0] + kk2[1]); \
    bb10 = *(const short8*)((Bl) + boffs[1] + kk2[0]); \
    bb11 = *(const short8*)((Bl) + boffs[1] + kk2[1]); \
    bb20 = *(const short8*)((Bl) + boffs[2] + kk2[0]); \
    bb21 = *(const short8*)((Bl) + boffs[2] + kk2[1]); \
    bb30 = *(const short8*)((Bl) + boffs[3] + kk2[0]); \
    bb31 = *(const short8*)((Bl) + boffs[3] + kk2[1]);

// one-barrier phase: reads+stage issued, wait own lgkm, MFMA, (vmcnt,) barrier
#define PH_MFMA(Q) \
    asm volatile("s_waitcnt lgkmcnt(0)" ::: "memory"); \
    __builtin_amdgcn_sched_barrier(0); \
    __builtin_amdgcn_s_setprio(1); \
    acc[2*(Q)][0]   = mfma16(a00, bb00, acc[2*(Q)][0]); \
    acc[2*(Q)][0]   = mfma16(a01, bb01, acc[2*(Q)][0]); \
    acc[2*(Q)][1]   = mfma16(a00, bb10, acc[2*(Q)][1]); \
    acc[2*(Q)][1]   = mfma16(a01, bb11, acc[2*(Q)][1]); \
    acc[2*(Q)][2]   = mfma16(a00, bb20, acc[2*(Q)][2]); \
    acc[2*(Q)][2]   = mfma16(a01, bb21, acc[2*(Q)][2]); \
    acc[2*(Q)][3]   = mfma16(a00, bb30, acc[2*(Q)][3]); \
    acc[2*(Q)][3]   = mfma16(a01, bb31, acc[2*(Q)][3]); \
    acc[2*(Q)+1][0] = mfma16(a10, bb00, acc[2*(Q)+1][0]); \
    acc[2*(Q)+1][0] = mfma16(a11, bb01, acc[2*(Q)+1][0]); \
    acc[2*(Q)+1][1] = mfma16(a10, bb10, acc[2*(Q)+1][1]); \
    acc[2*(Q)+1][1] = mfma16(a11, bb11, acc[2*(Q)+1][1]); \
    acc[2*(Q)+1][2] = mfma16(a10, bb20, acc[2*(Q)+1][2]); \
    acc[2*(Q)+1][2] = mfma16(a11, bb21, acc[2*(Q)+1][2]); \
    acc[2*(Q)+1][3] = mfma16(a10, bb30, acc[2*(Q)+1][3]); \
    acc[2*(Q)+1][3] = mfma16(a11, bb31, acc[2*(Q)+1][3]); \
    __builtin_amdgcn_s_setprio(0);

#define PH_END  __builtin_amdgcn_s_barrier(); }

#define GEMM_BODY(MORE) \
        PH_READA(A0lds, 0) PH_READB(B0lds) \
        stageA(v, A1lds, 0); stageA(v, A1lds, 1); \
        PH_MFMA(0) PH_END \
        PH_READA(A0lds, 1) \
        if (MORE) stageB(u2, B0lds, 0); \
        PH_MFMA(1) PH_END \
        PH_READA(A0lds, 2) \
        if (MORE) stageB(u2, B0lds, 1); \
        PH_MFMA(2) PH_END \
        PH_READA(A0lds, 3) \
        PH_MFMA(3) \
        if (MORE) { asm volatile("s_waitcnt vmcnt(4)" ::: "memory"); } \
        else      { asm volatile("s_waitcnt vmcnt(0)" ::: "memory"); } \
        PH_END \
        PH_READA(A1lds, 0) PH_READB(B1lds) \
        if (MORE) stageA(u2, A0lds, 0); \
        PH_MFMA(0) PH_END \
        PH_READA(A1lds, 1) \
        if (MORE) stageA(u2, A0lds, 1); \
        PH_MFMA(1) PH_END \
        PH_READA(A1lds, 2) \
        if (MORE) stageB(v2, B1lds, 0); \
        PH_MFMA(2) PH_END \
        PH_READA(A1lds, 3) \
        if (MORE) stageB(v2, B1lds, 1); \
        PH_MFMA(3) \
        if (MORE) { asm volatile("s_waitcnt vmcnt(4)" ::: "memory"); } \
        PH_END

__global__ __launch_bounds__(512, 2) void gemm1_kernel(
    const unsigned short* __restrict__ A, const unsigned short* __restrict__ Bw,
    const float* __restrict__ bias, unsigned short* __restrict__ Cbf) {
    constexpr int K = 512;
    constexpr int NT = K / 64;
    constexpr int NXT = 8;                 // N = 2048
    constexpr int NC = 2048;

    extern __shared__ unsigned short lds[];
    unsigned short* A0lds = lds;
    unsigned short* B0lds = lds + 16384;
    unsigned short* A1lds = lds + 32768;
    unsigned short* B1lds = lds + 49152;

    const int nwg = (int)gridDim.x;
    const int orig = (int)blockIdx.x;
    const int q8 = nwg >> 3, r8 = nwg & 7;
    const int xcd = orig & 7, idx = orig >> 3;
    const int w = (xcd < r8 ? xcd * (q8 + 1) : r8 * (q8 + 1) + (xcd - r8) * q8) + idx;
    const int mt_i = w / NXT, nt_i = w % NXT;
    const size_t arow0 = (size_t)mt_i * 256;
    const int n0 = nt_i * 256;

    const int tid = threadIdx.x;
    const int l = tid & 63, wv = tid >> 6;
    const int wm = wv >> 2, wn = wv & 3;
    const int lr = l & 15, lq = l >> 4;

    const int srow = tid >> 3;
    const int skb = ((((tid & 7) << 4) ^ ((srow & 7) << 4)) >> 1);

    const int sw = (lr & 7) << 4;
    int kk2[2];
    kk2[0] = ((lq * 16) ^ sw) >> 1;
    kk2[1] = ((64 + lq * 16) ^ sw) >> 1;
    int aoffs[8], boffs[4];
#pragma unroll
    for (int mf = 0; mf < 8; ++mf) aoffs[mf] = (wm * 128 + mf * 16 + lr) * 64;
#pragma unroll
    for (int nf = 0; nf < 4; ++nf) boffs[nf] = (wn * 64 + nf * 16 + lr) * 64;

    f32x4 acc[8][4];
#pragma unroll
    for (int i = 0; i < 8; ++i)
#pragma unroll
        for (int j = 0; j < 4; ++j) acc[i][j] = (f32x4){0.f, 0.f, 0.f, 0.f};

    short8 bb00, bb01, bb10, bb11, bb20, bb21, bb30, bb31;

    // hoisted thread-invariant staging bases
    const unsigned short* Ath = A + (arow0 + srow) * (size_t)K + skb;
    const unsigned short* Bth = Bw + ((size_t)n0 + srow) * K + skb;

    auto stageA = [&](int tile, unsigned short* dst, int half) {
        const unsigned short* g = Ath + (size_t)half * (128 * K) + tile * 64;
        unsigned short* d = dst + half * 8192 + tid * 8;
        GLOAD16(g, d);
        GLOAD16(g + (size_t)64 * K, d + 4096);
    };
    auto stageB = [&](int tile, unsigned short* dst, int half) {
        const unsigned short* g = Bth + (size_t)half * (128 * K) + tile * 64;
        unsigned short* d = dst + half * 8192 + tid * 8;
        GLOAD16(g, d);
        GLOAD16(g + (size_t)64 * K, d + 4096);
    };

    stageB(0, B0lds, 0);
    stageB(0, B0lds, 1);
    stageA(0, A0lds, 0);
    stageA(0, A0lds, 1);
    stageB(1, B1lds, 0);
    stageB(1, B1lds, 1);
    asm volatile("s_waitcnt vmcnt(4)" ::: "memory");
    __builtin_amdgcn_s_barrier();

#pragma unroll 1
    for (int t = 0; t < NT / 2 - 1; ++t) {
        const int v = 2 * t + 1, u2 = 2 * t + 2, v2 = 2 * t + 3;
        GEMM_BODY(1)
    }
    {
        const int t = NT / 2 - 1;
        const int v = 2 * t + 1, u2 = 2 * t + 2, v2 = 2 * t + 3;
        (void)u2; (void)v2;
        GEMM_BODY(0)
    }

    float bv[4];
#pragma unroll
    for (int nf = 0; nf < 4; ++nf) bv[nf] = bias[n0 + wn * 64 + nf * 16 + lr];

#pragma unroll
    for (int mf = 0; mf < 8; ++mf) {
#pragma unroll
        for (int qq = 0; qq < 4; ++qq) {
            long row = (long)arow0 + wm * 128 + mf * 16 + lq * 4 + qq;
#pragma unroll
            for (int nf = 0; nf < 4; ++nf) {
                int col = n0 + wn * 64 + nf * 16 + lr;
                float vvv = acc[mf][nf][qq] + bv[nf];
                Cbf[(size_t)row * NC + col] = f2bf(fmaxf(vvv, 0.f));
            }
        }
    }
}

// ---------- FFN2 + LN2 fused: y = LN(t1 @ W2^T + bW2 + h) ----------
// BM=128 x BN=512 (full rows). Same read layout/ledger as round 5; one barrier/phase.

#define Q2_READB(Bl) \
    _Pragma("unroll") \
    for (int nf = 0; nf < 8; ++nf) { \
        bb[2 * nf]     = *(const short8*)((Bl) + boffs2[nf] + kk2[0]); \
        bb[2 * nf + 1] = *(const short8*)((Bl) + boffs2[nf] + kk2[1]); \
    }

#define Q2_PH(Al, Q) { short8 a0_, a1_; \
    a0_ = *(const short8*)((Al) + aoffs2[Q] + kk2[0]); \
    a1_ = *(const short8*)((Al) + aoffs2[Q] + kk2[1]);

#define Q2_MFMA(Q) \
    asm volatile("s_waitcnt lgkmcnt(0)" ::: "memory"); \
    __builtin_amdgcn_sched_barrier(0); \
    __builtin_amdgcn_s_setprio(1); \
    _Pragma("unroll") \
    for (int nf = 0; nf < 8; ++nf) { \
        acc[Q][nf] = mfma16(a0_, bb[2 * nf],     acc[Q][nf]); \
        acc[Q][nf] = mfma16(a1_, bb[2 * nf + 1], acc[Q][nf]); \
    } \
    __builtin_amdgcn_s_setprio(0);

#define Q2_END  __builtin_amdgcn_s_barrier(); }

#define BODY2(MORE) \
        Q2_READB(B0l) \
        Q2_PH(A0l, 0) stageA(v, A1l); Q2_MFMA(0) Q2_END \
        Q2_PH(A0l, 1) if (MORE) stageB(u2, B0l, 0); Q2_MFMA(1) Q2_END \
        Q2_PH(A0l, 2) if (MORE) stageB(u2, B0l, 1); Q2_MFMA(2) Q2_END \
        Q2_PH(A0l, 3) Q2_MFMA(3) \
        if (MORE) { asm volatile("s_waitcnt vmcnt(8)" ::: "memory"); } \
        else      { asm volatile("s_waitcnt vmcnt(0)" ::: "memory"); } \
        Q2_END \
        Q2_READB(B1l) \
        Q2_PH(A1l, 0) if (MORE) stageA(u2, A0l); Q2_MFMA(0) Q2_END \
        Q2_PH(A1l, 1) if (MORE) stageB(v2, B1l, 0); Q2_MFMA(1) Q2_END \
        Q2_PH(A1l, 2) if (MORE) stageB(v2, B1l, 1); Q2_MFMA(2) Q2_END \
        Q2_PH(A1l, 3) Q2_MFMA(3) \
        if (MORE) { asm volatile("s_waitcnt vmcnt(8)" ::: "memory"); } \
        Q2_END

__global__ __launch_bounds__(512, 2) void gemm2ln_kernel(
    const unsigned short* __restrict__ A,      // t1 chunk [rows][2048]
    const unsigned short* __restrict__ Bw,     // W2T [512][2048]
    const float* __restrict__ bias,            // bW2
    const unsigned short* __restrict__ hres,   // h bf16 (full, global rows)
    const float* __restrict__ g2, const float* __restrict__ b2,
    float* __restrict__ y, long out_row0) {
    constexpr int K = 2048;
    constexpr int NT = K / 64;                 // 32 K-tiles

    extern __shared__ unsigned short lds[];
    unsigned short* A0l = lds;                 // [128][64]
    unsigned short* A1l = lds + 8192;
    unsigned short* B0l = lds + 16384;         // [512][64]
    unsigned short* B1l = lds + 49152;

    const int nwg = (int)gridDim.x;
    const int orig = (int)blockIdx.x;
    const int q8 = nwg >> 3, r8 = nwg & 7;
    const int xcd = orig & 7, idx = orig >> 3;
    const int w = (xcd < r8 ? xcd * (q8 + 1) : r8 * (q8 + 1) + (xcd - r8) * q8) + idx;
    const size_t arow0 = (size_t)w * 128;

    const int tid = threadIdx.x;
    const int l = tid & 63, wv = tid >> 6;
    const int wm = wv & 1, wn = wv >> 1;       // 2 m-waves x 4 n-waves
    const int lr = l & 15, lq = l >> 4;

    const int srow = tid >> 3;
    const int skb = ((((tid & 7) << 4) ^ ((srow & 7) << 4)) >> 1);

    const int sw = (lr & 7) << 4;
    int kk2[2];
    kk2[0] = ((lq * 16) ^ sw) >> 1;
    kk2[1] = ((64 + lq * 16) ^ sw) >> 1;
    int aoffs2[4], boffs2[8];
#pragma unroll
    for (int mf = 0; mf < 4; ++mf) aoffs2[mf] = (wm * 64 + mf * 16 + lr) * 64;
#pragma unroll
    for (int nf = 0; nf < 8; ++nf) boffs2[nf] = (wn * 128 + nf * 16 + lr) * 64;

    f32x4 acc[4][8];
#pragma unroll
    for (int i = 0; i < 4; ++i)
#pragma unroll
        for (int j = 0; j < 8; ++j) acc[i][j] = (f32x4){0.f, 0.f, 0.f, 0.f};

    short8 bb[16];

    // hoisted thread-invariant staging bases
    const unsigned short* Ath = A + (arow0 + srow) * (size_t)K + skb;
    const unsigned short* Bth = Bw + (size_t)srow * K + skb;

    auto stageA = [&](int tile, unsigned short* dst) {
        const unsigned short* g = Ath + tile * 64;
        unsigned short* d = dst + tid * 8;
        GLOAD16(g, d);
        GLOAD16(g + (size_t)64 * K, d + 4096);
    };
    auto stageB = [&](int tile, unsigned short* dst, int half) {
        const unsigned short* g = Bth + (size_t)(half * 256) * K + tile * 64;
        unsigned short* d = dst + half * 16384 + tid * 8;
#pragma unroll
        for (int i = 0; i < 4; ++i)
            GLOAD16(g + (size_t)(64 * i) * K, d + 4096 * i);
    };

    // prologue: B(0) [8], A(0) [2], B(1) [8]; wait first 10 -> vmcnt(8)
    stageB(0, B0l, 0);
    stageB(0, B0l, 1);
    stageA(0, A0l);
    stageB(1, B1l, 0);
    stageB(1, B1l, 1);
    asm volatile("s_waitcnt vmcnt(8)" ::: "memory");
    __builtin_amdgcn_s_barrier();

#pragma unroll 1
    for (int t = 0; t < NT / 2 - 1; ++t) {
        const int v = 2 * t + 1, u2 = 2 * t + 2, v2 = 2 * t + 3;
        BODY2(1)
    }
    {
        const int t = NT / 2 - 1;
        const int v = 2 * t + 1, u2 = 2 * t + 2, v2 = 2 * t + 3;
        (void)u2; (void)v2;
        BODY2(0)
    }

    // ---- epilogue: bias + bf16-h residual, row LN across block, write y ----
    float* red = (float*)lds;                  // [sum:4x128][sq:4x128] floats
    float bv2[8], gv2[8], bb2[8];
#pragma unroll
    for (int nf = 0; nf < 8; ++nf) {
        int col = wn * 128 + nf * 16 + lr;
        bv2[nf] = bias[col];
        gv2[nf] = g2[col];
        bb2[nf] = b2[col];
    }

#pragma unroll
    for (int mf = 0; mf < 4; ++mf) {
#pragma unroll
        for (int qq = 0; qq < 4; ++qq) {
            int lrow = wm * 64 + mf * 16 + lq * 4 + qq;
            long grow = out_row0 + (long)arow0 + lrow;
            const unsigned short* hr = hres + (size_t)grow * 512 + wn * 128 + lr;
            float s = 0.f, s2 = 0.f;
#pragma unroll
            for (int nf = 0; nf < 8; ++nf) {
                float z = acc[mf][nf][qq] + bv2[nf] + bf2f(hr[nf * 16]);
                acc[mf][nf][qq] = z;
                s += z;
                s2 += z * z;
            }
            s += __shfl_xor(s, 1, 16); s2 += __shfl_xor(s2, 1, 16);
            s += __shfl_xor(s, 2, 16); s2 += __shfl_xor(s2, 2, 16);
            s += __shfl_xor(s, 4, 16); s2 += __shfl_xor(s2, 4, 16);
            s += __shfl_xor(s, 8, 16); s2 += __shfl_xor(s2, 8, 16);
            if (lr == 0) {
                red[wn * 128 + lrow] = s;
                red[512 + wn * 128 + lrow] = s2;
            }
        }
    }
    __syncthreads();

#pragma unroll
    for (int mf = 0; mf < 4; ++mf) {
#pragma unroll
        for (int qq = 0; qq < 4; ++qq) {
            int lrow = wm * 64 + mf * 16 + lq * 4 + qq;
            long grow = out_row0 + (long)arow0 + lrow;
            float s = red[lrow] + red[128 + lrow] + red[256 + lrow] + red[384 + lrow];
            float s2 = red[512 + lrow] + red[640 + lrow] + red[768 + lrow] + red[896 + lrow];
            float mu = s * (1.f / 512.f);
            float var = s2 * (1.f / 512.f) - mu * mu;
            float inv = rsqrtf(var + 1e-5f);
            float* yr = y + (size_t)grow * 512 + wn * 128 + lr;
#pragma unroll
            for (int nf = 0; nf < 8; ++nf)
                yr[nf * 16] = (acc[mf][nf][qq] - mu) * inv * gv2[nf] + bb2[nf];
        }
    }
}

// ---------- host ----------
extern "C" void kernel_launch(void* const* d_in, const int* in_sizes, int n_in,
                              void* d_out, int out_size, void* d_ws, size_t ws_size,
                              hipStream_t stream) {
    const float* x = (const float*)d_in[0];
    const void* mask = d_in[1];
    const float* g1 = (const float*)d_in[2];
    const float* b1 = (const float*)d_in[3];
    const float* g2 = (const float*)d_in[4];
    const float* b2 = (const float*)d_in[5];
    const float* W1 = (const float*)d_in[6];
    const float* bW1 = (const float*)d_in[7];
    const float* W2 = (const float*)d_in[8];
    const float* bW2 = (const float*)d_in[9];

    float* y = (float*)d_out;
    float* attn = y + Y_ELEMS;
    char* ws = (char*)d_ws;
    unsigned short* W1T = (unsigned short*)(ws);                 // 2 MiB  [2048][512]
    unsigned short* W2T = (unsigned short*)(ws + 2097152);       // 2 MiB  [512][2048]
    int* flag = (int*)(ws + 4194304);
    unsigned short* h = (unsigned short*)(ws + 4194560);         // 64 MiB [65536][512] bf16
    unsigned short* t1 = (unsigned short*)(ws + 71303424ULL);    // [chunk*256][2048] bf16

    hipFuncSetAttribute((const void*)gemm1_kernel,
                        hipFuncAttributeMaxDynamicSharedMemorySize, 131072);
    hipFuncSetAttribute((const void*)gemm2ln_kernel,
                        hipFuncAttributeMaxDynamicSharedMemorySize, 163840);

    long cap256 = ((long)ws_size - 71303424L) / (256L * 2048L * 2L);
    if (cap256 < 1) cap256 = 1;
    if (cap256 > 256) cap256 = 256;

    transpose_kernel<<<dim3(64, 16), dim3(256), 0, stream>>>(W1, W1T, 512, 2048);
    transpose_kernel<<<dim3(16, 64), dim3(256), 0, stream>>>(W2, W2T, 2048, 512);
    detect_kernel<<<1, 256, 0, stream>>>((const unsigned char*)mask, flag);
    stage1_kernel<<<4096, 256, 0, stream>>>(x, (const unsigned char*)mask, (const int*)mask,
                                            flag, g1, b1, attn, h);
    for (long t0 = 0; t0 < 256; t0 += cap256) {
        long mt = (256 - t0 < cap256) ? (256 - t0) : cap256;
        long row0 = t0 * 256;
        gemm1_kernel<<<dim3((unsigned)(8 * mt)), 512, 131072, stream>>>(
            h + (size_t)row0 * 512, W1T, bW1, t1);
        gemm2ln_kernel<<<dim3((unsigned)(2 * mt)), 512, 163840, stream>>>(
            t1, W2T, bW2, h, g2, b2, y, row0);
    }
}

// Round 8
// 404.218 us; speedup vs baseline: 1.6038x; 1.0046x over previous
//
#include <hip/hip_runtime.h>

// ---------- types & helpers ----------
typedef float  f32x4 __attribute__((ext_vector_type(4)));
typedef short  short8 __attribute__((ext_vector_type(8)));

__device__ __forceinline__ unsigned short f2bf(float f) {
    unsigned u = __builtin_bit_cast(unsigned, f);
    unsigned r = u + 0x7FFFu + ((u >> 16) & 1u);
    return (unsigned short)(r >> 16);
}
__device__ __forceinline__ float bf2f(unsigned short b) {
    return __builtin_bit_cast(float, (unsigned)b << 16);
}

__device__ __forceinline__ f32x4 mfma16(short8 a, short8 b, f32x4 c) {
    return __builtin_amdgcn_mfma_f32_16x16x32_bf16(a, b, c, 0, 0, 0);
}

#define GLOAD16(gp, lp) \
    __builtin_amdgcn_global_load_lds((const __attribute__((address_space(1))) unsigned int*)(gp), \
                                     (__attribute__((address_space(3))) unsigned int*)(lp), 16, 0, 0)

// ---------- constants ----------
#define BT   4096
#define NTOK 16
#define DDIM 512
#define Y_ELEMS 33554432ULL        // BT*NTOK*DDIM
#define XS_STRIDE 516

// ---------- weight transpose fp32 [R][C] -> bf16 [C][R] ----------
__global__ __launch_bounds__(256) void transpose_kernel(const float* __restrict__ in,
                                                        unsigned short* __restrict__ out,
                                                        int R, int C) {
    __shared__ float tile[32][33];
    const int tx = threadIdx.x & 31, ty = threadIdx.x >> 5;
    const int c0 = blockIdx.x * 32, r0 = blockIdx.y * 32;
#pragma unroll
    for (int i = 0; i < 4; ++i)
        tile[ty + 8 * i][tx] = in[(size_t)(r0 + ty + 8 * i) * C + c0 + tx];
    __syncthreads();
#pragma unroll
    for (int i = 0; i < 4; ++i)
        out[(size_t)(c0 + ty + 8 * i) * R + r0 + tx] = f2bf(tile[tx][ty + 8 * i]);
}

// ---------- mask dtype detection ----------
__global__ void detect_kernel(const unsigned char* __restrict__ m, int* __restrict__ flag) {
    __shared__ int any;
    if (threadIdx.x == 0) any = 0;
    __syncthreads();
    int loc = 0;
    for (int i = threadIdx.x; i < 4096; i += 256)
        if (i & 3) loc |= m[i];
    if (loc) atomicOr(&any, 1);
    __syncthreads();
    if (threadIdx.x == 0) *flag = any ? 1 : 0;
}

// ---------- stage 1 (pure fp32): scores, softmax, p@x, LN1 -> h (bf16 only) ----------
__global__ __launch_bounds__(256) void stage1_kernel(
    const float* __restrict__ x,
    const unsigned char* __restrict__ mask_u8, const int* __restrict__ mask_i32,
    const int* __restrict__ flagp,
    const float* __restrict__ g1, const float* __restrict__ b1,
    float* __restrict__ attn_out, unsigned short* __restrict__ hbf) {
    __shared__ float xs[NTOK * XS_STRIDE];
    __shared__ float p_lds[256];

    const int b = blockIdx.x, t = threadIdx.x;
    const float* xb = x + (size_t)b * (NTOK * DDIM);

#pragma unroll
    for (int i = 0; i < 8; ++i) {
        int s = t + 256 * i;
        int r = s >> 7, c4 = s & 127;
        f32x4 v = ((const f32x4*)xb)[s];
        *(f32x4*)(&xs[r * XS_STRIDE + c4 * 4]) = v;
    }
    __syncthreads();

    const int r = t >> 4, c = t & 15;
    {
        const f32x4* xr = (const f32x4*)(&xs[r * XS_STRIDE]);
        const f32x4* xc = (const f32x4*)(&xs[c * XS_STRIDE]);
        f32x4 d4 = {0.f, 0.f, 0.f, 0.f};
#pragma unroll 8
        for (int u = 0; u < 128; ++u) d4 += xr[u] * xc[u];
        float s_rc = (d4.x + d4.y + d4.z + d4.w) * 0.04419417382415922f;

        const int flag = *flagp;
        size_t midx = (size_t)b * 256 + t;
        bool msk = flag ? (mask_u8[midx] != 0) : (mask_i32[midx] != 0);
        float sv = msk ? -1e30f : s_rc;
        float mx = sv;
        mx = fmaxf(mx, __shfl_xor(mx, 1, 16));
        mx = fmaxf(mx, __shfl_xor(mx, 2, 16));
        mx = fmaxf(mx, __shfl_xor(mx, 4, 16));
        mx = fmaxf(mx, __shfl_xor(mx, 8, 16));
        float e = msk ? 0.f : expf(sv - mx);
        float sum = e;
        sum += __shfl_xor(sum, 1, 16);
        sum += __shfl_xor(sum, 2, 16);
        sum += __shfl_xor(sum, 4, 16);
        sum += __shfl_xor(sum, 8, 16);
        float p = e / sum;
        p_lds[t] = p;
        attn_out[midx] = p;
    }
    __syncthreads();

    const int r2 = t >> 4, tc = t & 15;
    f32x4 acc[8];
#pragma unroll
    for (int j = 0; j < 8; ++j) acc[j] = (f32x4){0.f, 0.f, 0.f, 0.f};
    for (int c2 = 0; c2 < 16; ++c2) {
        float pw = p_lds[r2 * 16 + c2];
        const f32x4* xrow = (const f32x4*)(&xs[c2 * XS_STRIDE]);
#pragma unroll
        for (int j = 0; j < 8; ++j) acc[j] += pw * xrow[tc + 16 * j];
    }

    const f32x4* xme = (const f32x4*)(&xs[r2 * XS_STRIDE]);
    f32x4 vv[8];
    float s1 = 0.f, s2 = 0.f;
#pragma unroll
    for (int j = 0; j < 8; ++j) {
        f32x4 v = xme[tc + 16 * j] + acc[j];
        vv[j] = v;
        s1 += v.x + v.y + v.z + v.w;
        s2 += v.x * v.x + v.y * v.y + v.z * v.z + v.w * v.w;
    }
    s1 += __shfl_xor(s1, 1, 16); s2 += __shfl_xor(s2, 1, 16);
    s1 += __shfl_xor(s1, 2, 16); s2 += __shfl_xor(s2, 2, 16);
    s1 += __shfl_xor(s1, 4, 16); s2 += __shfl_xor(s2, 4, 16);
    s1 += __shfl_xor(s1, 8, 16); s2 += __shfl_xor(s2, 8, 16);
    float mu = s1 * (1.f / 512.f);
    float var = s2 * (1.f / 512.f) - mu * mu;
    float inv = rsqrtf(var + 1e-5f);

    unsigned short* hrow = hbf + (size_t)(b * NTOK + r2) * DDIM;
#pragma unroll
    for (int j = 0; j < 8; ++j) {
        int u = tc + 16 * j;
        f32x4 gv = ((const f32x4*)g1)[u];
        f32x4 bv = ((const f32x4*)b1)[u];
        f32x4 o = (vv[j] - mu) * inv * gv + bv;
        uint2 pk;
        pk.x = (unsigned)f2bf(o.x) | ((unsigned)f2bf(o.y) << 16);
        pk.y = (unsigned)f2bf(o.z) | ((unsigned)f2bf(o.w) << 16);
        *(uint2*)(hrow + u * 4) = pk;
    }
}

// ---------- FFN1: 8-phase 256x256 GEMM, one barrier per phase (round-7 proven) ----------
#define PH_READA(Al, Q) { short8 a00, a01, a10, a11; \
    a00 = *(const short8*)((Al) + aoffs[2*(Q)]   + kk2[0]); \
    a01 = *(const short8*)((Al) + aoffs[2*(Q)]   + kk2[1]); \
    a10 = *(const short8*)((Al) + aoffs[2*(Q)+1] + kk2[0]); \
    a11 = *(const short8*)((Al) + aoffs[2*(Q)+1] + kk2[1]);

#define PH_READB(Bl) \
    bb00 = *(const short8*)((Bl) + boffs[0] + kk2[0]); \
    bb01 = *(const short8*)((Bl) + boffs[0] + kk2[1]); \
    bb10 = *(const short8*)((Bl) + boffs[1] + kk2[0]); \
    bb11 = *(const short8*)((Bl) + boffs[1] + kk2[1]); \
    bb20 = *(const short8*)((Bl) + boffs[2] + kk2[0]); \
    bb21 = *(const short8*)((Bl) + boffs[2] + kk2[1]); \
    bb30 = *(const short8*)((Bl) + boffs[3] + kk2[0]); \
    bb31 = *(const short8*)((Bl) + boffs[3] + kk2[1]);

#define PH_MFMA(Q) \
    asm volatile("s_waitcnt lgkmcnt(0)" ::: "memory"); \
    __builtin_amdgcn_sched_barrier(0); \
    __builtin_amdgcn_s_setprio(1); \
    acc[2*(Q)][0]   = mfma16(a00, bb00, acc[2*(Q)][0]); \
    acc[2*(Q)][0]   = mfma16(a01, bb01, acc[2*(Q)][0]); \
    acc[2*(Q)][1]   = mfma16(a00, bb10, acc[2*(Q)][1]); \
    acc[2*(Q)][1]   = mfma16(a01, bb11, acc[2*(Q)][1]); \
    acc[2*(Q)][2]   = mfma16(a00, bb20, acc[2*(Q)][2]); \
    acc[2*(Q)][2]   = mfma16(a01, bb21, acc[2*(Q)][2]); \
    acc[2*(Q)][3]   = mfma16(a00, bb30, acc[2*(Q)][3]); \
    acc[2*(Q)][3]   = mfma16(a01, bb31, acc[2*(Q)][3]); \
    acc[2*(Q)+1][0] = mfma16(a10, bb00, acc[2*(Q)+1][0]); \
    acc[2*(Q)+1][0] = mfma16(a11, bb01, acc[2*(Q)+1][0]); \
    acc[2*(Q)+1][1] = mfma16(a10, bb10, acc[2*(Q)+1][1]); \
    acc[2*(Q)+1][1] = mfma16(a11, bb11, acc[2*(Q)+1][1]); \
    acc[2*(Q)+1][2] = mfma16(a10, bb20, acc[2*(Q)+1][2]); \
    acc[2*(Q)+1][2] = mfma16(a11, bb21, acc[2*(Q)+1][2]); \
    acc[2*(Q)+1][3] = mfma16(a10, bb30, acc[2*(Q)+1][3]); \
    acc[2*(Q)+1][3] = mfma16(a11, bb31, acc[2*(Q)+1][3]); \
    __builtin_amdgcn_s_setprio(0);

#define PH_END  __builtin_amdgcn_s_barrier(); }

#define GEMM_BODY(MORE) \
        PH_READA(A0lds, 0) PH_READB(B0lds) \
        stageA(v, A1lds, 0); stageA(v, A1lds, 1); \
        PH_MFMA(0) PH_END \
        PH_READA(A0lds, 1) \
        if (MORE) stageB(u2, B0lds, 0); \
        PH_MFMA(1) PH_END \
        PH_READA(A0lds, 2) \
        if (MORE) stageB(u2, B0lds, 1); \
        PH_MFMA(2) PH_END \
        PH_READA(A0lds, 3) \
        PH_MFMA(3) \
        if (MORE) { asm volatile("s_waitcnt vmcnt(4)" ::: "memory"); } \
        else      { asm volatile("s_waitcnt vmcnt(0)" ::: "memory"); } \
        PH_END \
        PH_READA(A1lds, 0) PH_READB(B1lds) \
        if (MORE) stageA(u2, A0lds, 0); \
        PH_MFMA(0) PH_END \
        PH_READA(A1lds, 1) \
        if (MORE) stageA(u2, A0lds, 1); \
        PH_MFMA(1) PH_END \
        PH_READA(A1lds, 2) \
        if (MORE) stageB(v2, B1lds, 0); \
        PH_MFMA(2) PH_END \
        PH_READA(A1lds, 3) \
        if (MORE) stageB(v2, B1lds, 1); \
        PH_MFMA(3) \
        if (MORE) { asm volatile("s_waitcnt vmcnt(4)" ::: "memory"); } \
        PH_END

__global__ __launch_bounds__(512, 2) void gemm1_kernel(
    const unsigned short* __restrict__ A, const unsigned short* __restrict__ Bw,
    const float* __restrict__ bias, unsigned short* __restrict__ Cbf) {
    constexpr int K = 512;
    constexpr int NT = K / 64;
    constexpr int NXT = 8;                 // N = 2048
    constexpr int NC = 2048;

    extern __shared__ unsigned short lds[];
    unsigned short* A0lds = lds;
    unsigned short* B0lds = lds + 16384;
    unsigned short* A1lds = lds + 32768;
    unsigned short* B1lds = lds + 49152;

    const int nwg = (int)gridDim.x;
    const int orig = (int)blockIdx.x;
    const int q8 = nwg >> 3, r8 = nwg & 7;
    const int xcd = orig & 7, idx = orig >> 3;
    const int w = (xcd < r8 ? xcd * (q8 + 1) : r8 * (q8 + 1) + (xcd - r8) * q8) + idx;
    const int mt_i = w / NXT, nt_i = w % NXT;
    const size_t arow0 = (size_t)mt_i * 256;
    const int n0 = nt_i * 256;

    const int tid = threadIdx.x;
    const int l = tid & 63, wv = tid >> 6;
    const int wm = wv >> 2, wn = wv & 3;
    const int lr = l & 15, lq = l >> 4;

    const int srow = tid >> 3;
    const int skb = ((((tid & 7) << 4) ^ ((srow & 7) << 4)) >> 1);

    const int sw = (lr & 7) << 4;
    int kk2[2];
    kk2[0] = ((lq * 16) ^ sw) >> 1;
    kk2[1] = ((64 + lq * 16) ^ sw) >> 1;
    int aoffs[8], boffs[4];
#pragma unroll
    for (int mf = 0; mf < 8; ++mf) aoffs[mf] = (wm * 128 + mf * 16 + lr) * 64;
#pragma unroll
    for (int nf = 0; nf < 4; ++nf) boffs[nf] = (wn * 64 + nf * 16 + lr) * 64;

    f32x4 acc[8][4];
#pragma unroll
    for (int i = 0; i < 8; ++i)
#pragma unroll
        for (int j = 0; j < 4; ++j) acc[i][j] = (f32x4){0.f, 0.f, 0.f, 0.f};

    short8 bb00, bb01, bb10, bb11, bb20, bb21, bb30, bb31;

    const unsigned short* Ath = A + (arow0 + srow) * (size_t)K + skb;
    const unsigned short* Bth = Bw + ((size_t)n0 + srow) * K + skb;

    auto stageA = [&](int tile, unsigned short* dst, int half) {
        const unsigned short* g = Ath + (size_t)half * (128 * K) + tile * 64;
        unsigned short* d = dst + half * 8192 + tid * 8;
        GLOAD16(g, d);
        GLOAD16(g + (size_t)64 * K, d + 4096);
    };
    auto stageB = [&](int tile, unsigned short* dst, int half) {
        const unsigned short* g = Bth + (size_t)half * (128 * K) + tile * 64;
        unsigned short* d = dst + half * 8192 + tid * 8;
        GLOAD16(g, d);
        GLOAD16(g + (size_t)64 * K, d + 4096);
    };

    stageB(0, B0lds, 0);
    stageB(0, B0lds, 1);
    stageA(0, A0lds, 0);
    stageA(0, A0lds, 1);
    stageB(1, B1lds, 0);
    stageB(1, B1lds, 1);
    asm volatile("s_waitcnt vmcnt(4)" ::: "memory");
    __builtin_amdgcn_s_barrier();

#pragma unroll 1
    for (int t = 0; t < NT / 2 - 1; ++t) {
        const int v = 2 * t + 1, u2 = 2 * t + 2, v2 = 2 * t + 3;
        GEMM_BODY(1)
    }
    {
        const int t = NT / 2 - 1;
        const int v = 2 * t + 1, u2 = 2 * t + 2, v2 = 2 * t + 3;
        (void)u2; (void)v2;
        GEMM_BODY(0)
    }

    float bv[4];
#pragma unroll
    for (int nf = 0; nf < 4; ++nf) bv[nf] = bias[n0 + wn * 64 + nf * 16 + lr];

#pragma unroll
    for (int mf = 0; mf < 8; ++mf) {
#pragma unroll
        for (int qq = 0; qq < 4; ++qq) {
            long row = (long)arow0 + wm * 128 + mf * 16 + lq * 4 + qq;
#pragma unroll
            for (int nf = 0; nf < 4; ++nf) {
                int col = n0 + wn * 64 + nf * 16 + lr;
                float vvv = acc[mf][nf][qq] + bv[nf];
                Cbf[(size_t)row * NC + col] = f2bf(fmaxf(vvv, 0.f));
            }
        }
    }
}

// ---------- FFN2 + LN2 fused: y = LN(t1 @ W2^T + bW2 + h) ----------
// BM=128 x BN=512, 8 waves (2m x 4n). BALANCED phases: A-frags (8 reads) at
// p0/p4 held in regs; B streams 4 reads/phase (n-group q). 16 MFMA/phase.
// Stage map: p0 B(v)h0, p1 B(v)h1+A(u2), p4 B(u2)h0, p5 B(u2)h1+A(v2).
// vmcnt(2) at p3/p7 (leaves newest A in flight). Numerics identical.

#define RD_A2(Al) \
    areg[0][0] = *(const short8*)((Al) + aoffs2[0] + kk2[0]); \
    areg[0][1] = *(const short8*)((Al) + aoffs2[0] + kk2[1]); \
    areg[1][0] = *(const short8*)((Al) + aoffs2[1] + kk2[0]); \
    areg[1][1] = *(const short8*)((Al) + aoffs2[1] + kk2[1]); \
    areg[2][0] = *(const short8*)((Al) + aoffs2[2] + kk2[0]); \
    areg[2][1] = *(const short8*)((Al) + aoffs2[2] + kk2[1]); \
    areg[3][0] = *(const short8*)((Al) + aoffs2[3] + kk2[0]); \
    areg[3][1] = *(const short8*)((Al) + aoffs2[3] + kk2[1]);

#define RD_B2(Bl, q) \
    bq00 = *(const short8*)((Bl) + boffs2[2*(q)]   + kk2[0]); \
    bq01 = *(const short8*)((Bl) + boffs2[2*(q)]   + kk2[1]); \
    bq10 = *(const short8*)((Bl) + boffs2[2*(q)+1] + kk2[0]); \
    bq11 = *(const short8*)((Bl) + boffs2[2*(q)+1] + kk2[1]);

#define MM_Q2(q) \
    asm volatile("s_waitcnt lgkmcnt(0)" ::: "memory"); \
    __builtin_amdgcn_sched_barrier(0); \
    __builtin_amdgcn_s_setprio(1); \
    _Pragma("unroll") \
    for (int mf = 0; mf < 4; ++mf) { \
        acc[mf][2*(q)]   = mfma16(areg[mf][0], bq00, acc[mf][2*(q)]); \
        acc[mf][2*(q)]   = mfma16(areg[mf][1], bq01, acc[mf][2*(q)]); \
        acc[mf][2*(q)+1] = mfma16(areg[mf][0], bq10, acc[mf][2*(q)+1]); \
        acc[mf][2*(q)+1] = mfma16(areg[mf][1], bq11, acc[mf][2*(q)+1]); \
    } \
    __builtin_amdgcn_s_setprio(0);

#define BAR2 __builtin_amdgcn_s_barrier();

#define BODY2(MORE) \
        /* p0 */ \
        RD_A2(A0l) RD_B2(B0l, 0) \
        stageB(v, B1l, 0); \
        MM_Q2(0) BAR2 \
        /* p1 */ \
        RD_B2(B0l, 1) \
        stageB(v, B1l, 1); \
        if (MORE) stageA(u2, A0l); \
        MM_Q2(1) BAR2 \
        /* p2 */ \
        RD_B2(B0l, 2) \
        MM_Q2(2) BAR2 \
        /* p3 */ \
        RD_B2(B0l, 3) \
        MM_Q2(3) \
        if (MORE) { asm volatile("s_waitcnt vmcnt(2)" ::: "memory"); } \
        else      { asm volatile("s_waitcnt vmcnt(0)" ::: "memory"); } \
        BAR2 \
        /* p4 */ \
        RD_A2(A1l) RD_B2(B1l, 0) \
        if (MORE) stageB(u2, B0l, 0); \
        MM_Q2(0) BAR2 \
        /* p5 */ \
        RD_B2(B1l, 1) \
        if (MORE) { stageB(u2, B0l, 1); stageA(v2, A1l); } \
        MM_Q2(1) BAR2 \
        /* p6 */ \
        RD_B2(B1l, 2) \
        MM_Q2(2) BAR2 \
        /* p7 */ \
        RD_B2(B1l, 3) \
        MM_Q2(3) \
        if (MORE) { asm volatile("s_waitcnt vmcnt(2)" ::: "memory"); } \
        else      { asm volatile("s_waitcnt vmcnt(0)" ::: "memory"); } \
        BAR2

__global__ __launch_bounds__(512, 2) void gemm2ln_kernel(
    const unsigned short* __restrict__ A,      // t1 chunk [rows][2048]
    const unsigned short* __restrict__ Bw,     // W2T [512][2048]
    const float* __restrict__ bias,            // bW2
    const unsigned short* __restrict__ hres,   // h bf16 (full, global rows)
    const float* __restrict__ g2, const float* __restrict__ b2,
    float* __restrict__ y, long out_row0) {
    constexpr int K = 2048;
    constexpr int NT = K / 64;                 // 32 K-tiles

    extern __shared__ unsigned short lds[];
    unsigned short* A0l = lds;                 // [128][64]
    unsigned short* A1l = lds + 8192;
    unsigned short* B0l = lds + 16384;         // [512][64]
    unsigned short* B1l = lds + 49152;

    const int nwg = (int)gridDim.x;
    const int orig = (int)blockIdx.x;
    const int q8 = nwg >> 3, r8 = nwg & 7;
    const int xcd = orig & 7, idx = orig >> 3;
    const int w = (xcd < r8 ? xcd * (q8 + 1) : r8 * (q8 + 1) + (xcd - r8) * q8) + idx;
    const size_t arow0 = (size_t)w * 128;

    const int tid = threadIdx.x;
    const int l = tid & 63, wv = tid >> 6;
    const int wm = wv & 1, wn = wv >> 1;       // 2 m-waves x 4 n-waves
    const int lr = l & 15, lq = l >> 4;

    const int srow = tid >> 3;
    const int skb = ((((tid & 7) << 4) ^ ((srow & 7) << 4)) >> 1);

    const int sw = (lr & 7) << 4;
    int kk2[2];
    kk2[0] = ((lq * 16) ^ sw) >> 1;
    kk2[1] = ((64 + lq * 16) ^ sw) >> 1;
    int aoffs2[4], boffs2[8];
#pragma unroll
    for (int mf = 0; mf < 4; ++mf) aoffs2[mf] = (wm * 64 + mf * 16 + lr) * 64;
#pragma unroll
    for (int nf = 0; nf < 8; ++nf) boffs2[nf] = (wn * 128 + nf * 16 + lr) * 64;

    f32x4 acc[4][8];
#pragma unroll
    for (int i = 0; i < 4; ++i)
#pragma unroll
        for (int j = 0; j < 8; ++j) acc[i][j] = (f32x4){0.f, 0.f, 0.f, 0.f};

    short8 areg[4][2];
    short8 bq00, bq01, bq10, bq11;

    const unsigned short* Ath = A + (arow0 + srow) * (size_t)K + skb;
    const unsigned short* Bth = Bw + (size_t)srow * K + skb;

    auto stageA = [&](int tile, unsigned short* dst) {
        const unsigned short* g = Ath + tile * 64;
        unsigned short* d = dst + tid * 8;
        GLOAD16(g, d);
        GLOAD16(g + (size_t)64 * K, d + 4096);
    };
    auto stageB = [&](int tile, unsigned short* dst, int half) {
        const unsigned short* g = Bth + (size_t)(half * 256) * K + tile * 64;
        unsigned short* d = dst + half * 16384 + tid * 8;
#pragma unroll
        for (int i = 0; i < 4; ++i)
            GLOAD16(g + (size_t)(64 * i) * K, d + 4096 * i);
    };

    // prologue: A(0)[2], B(0)h0[4], B(0)h1[4], A(1)[2]; wait 10 oldest -> vmcnt(2)
    stageA(0, A0l);
    stageB(0, B0l, 0);
    stageB(0, B0l, 1);
    stageA(1, A1l);
    asm volatile("s_waitcnt vmcnt(2)" ::: "memory");
    __builtin_amdgcn_s_barrier();

#pragma unroll 1
    for (int t = 0; t < NT / 2 - 1; ++t) {
        const int v = 2 * t + 1, u2 = 2 * t + 2, v2 = 2 * t + 3;
        BODY2(1)
    }
    {
        const int t = NT / 2 - 1;
        const int v = 2 * t + 1, u2 = 2 * t + 2, v2 = 2 * t + 3;
        (void)u2; (void)v2;
        BODY2(0)
    }

    // ---- epilogue: bias + bf16-h residual, row LN across block, write y ----
    float* red = (float*)lds;                  // [sum:4x128][sq:4x128] floats
    float bv2[8], gv2[8], bb2[8];
#pragma unroll
    for (int nf = 0; nf < 8; ++nf) {
        int col = wn * 128 + nf * 16 + lr;
        bv2[nf] = bias[col];
        gv2[nf] = g2[col];
        bb2[nf] = b2[col];
    }

#pragma unroll
    for (int mf = 0; mf < 4; ++mf) {
#pragma unroll
        for (int qq = 0; qq < 4; ++qq) {
            int lrow = wm * 64 + mf * 16 + lq * 4 + qq;
            long grow = out_row0 + (long)arow0 + lrow;
            const unsigned short* hr = hres + (size_t)grow * 512 + wn * 128 + lr;
            float s = 0.f, s2 = 0.f;
#pragma unroll
            for (int nf = 0; nf < 8; ++nf) {
                float z = acc[mf][nf][qq] + bv2[nf] + bf2f(hr[nf * 16]);
                acc[mf][nf][qq] = z;
                s += z;
                s2 += z * z;
            }
            s += __shfl_xor(s, 1, 16); s2 += __shfl_xor(s2, 1, 16);
            s += __shfl_xor(s, 2, 16); s2 += __shfl_xor(s2, 2, 16);
            s += __shfl_xor(s, 4, 16); s2 += __shfl_xor(s2, 4, 16);
            s += __shfl_xor(s, 8, 16); s2 += __shfl_xor(s2, 8, 16);
            if (lr == 0) {
                red[wn * 128 + lrow] = s;
                red[512 + wn * 128 + lrow] = s2;
            }
        }
    }
    __syncthreads();

#pragma unroll
    for (int mf = 0; mf < 4; ++mf) {
#pragma unroll
        for (int qq = 0; qq < 4; ++qq) {
            int lrow = wm * 64 + mf * 16 + lq * 4 + qq;
            long grow = out_row0 + (long)arow0 + lrow;
            float s = red[lrow] + red[128 + lrow] + red[256 + lrow] + red[384 + lrow];
            float s2 = red[512 + lrow] + red[640 + lrow] + red[768 + lrow] + red[896 + lrow];
            float mu = s * (1.f / 512.f);
            float var = s2 * (1.f / 512.f) - mu * mu;
            float inv = rsqrtf(var + 1e-5f);
            float* yr = y + (size_t)grow * 512 + wn * 128 + lr;
#pragma unroll
            for (int nf = 0; nf < 8; ++nf)
                yr[nf * 16] = (acc[mf][nf][qq] - mu) * inv * gv2[nf] + bb2[nf];
        }
    }
}

// ---------- host ----------
extern "C" void kernel_launch(void* const* d_in, const int* in_sizes, int n_in,
                              void* d_out, int out_size, void* d_ws, size_t ws_size,
                              hipStream_t stream) {
    const float* x = (const float*)d_in[0];
    const void* mask = d_in[1];
    const float* g1 = (const float*)d_in[2];
    const float* b1 = (const float*)d_in[3];
    const float* g2 = (const float*)d_in[4];
    const float* b2 = (const float*)d_in[5];
    const float* W1 = (const float*)d_in[6];
    const float* bW1 = (const float*)d_in[7];
    const float* W2 = (const float*)d_in[8];
    const float* bW2 = (const float*)d_in[9];

    float* y = (float*)d_out;
    float* attn = y + Y_ELEMS;
    char* ws = (char*)d_ws;
    unsigned short* W1T = (unsigned short*)(ws);                 // 2 MiB  [2048][512]
    unsigned short* W2T = (unsigned short*)(ws + 2097152);       // 2 MiB  [512][2048]
    int* flag = (int*)(ws + 4194304);
    unsigned short* h = (unsigned short*)(ws + 4194560);         // 64 MiB [65536][512] bf16
    unsigned short* t1 = (unsigned short*)(ws + 71303424ULL);    // [chunk*256][2048] bf16

    hipFuncSetAttribute((const void*)gemm1_kernel,
                        hipFuncAttributeMaxDynamicSharedMemorySize, 131072);
    hipFuncSetAttribute((const void*)gemm2ln_kernel,
                        hipFuncAttributeMaxDynamicSharedMemorySize, 163840);

    long cap256 = ((long)ws_size - 71303424L) / (256L * 2048L * 2L);
    if (cap256 < 1) cap256 = 1;
    if (cap256 > 256) cap256 = 256;

    transpose_kernel<<<dim3(64, 16), dim3(256), 0, stream>>>(W1, W1T, 512, 2048);
    transpose_kernel<<<dim3(16, 64), dim3(256), 0, stream>>>(W2, W2T, 2048, 512);
    detect_kernel<<<1, 256, 0, stream>>>((const unsigned char*)mask, flag);
    stage1_kernel<<<4096, 256, 0, stream>>>(x, (const unsigned char*)mask, (const int*)mask,
                                            flag, g1, b1, attn, h);
    for (long t0 = 0; t0 < 256; t0 += cap256) {
        long mt = (256 - t0 < cap256) ? (256 - t0) : cap256;
        long row0 = t0 * 256;
        gemm1_kernel<<<dim3((unsigned)(8 * mt)), 512, 131072, stream>>>(
            h + (size_t)row0 * 512, W1T, bW1, t1);
        gemm2ln_kernel<<<dim3((unsigned)(2 * mt)), 512, 163840, stream>>>(
            t1, W2T, bW2, h, g2, b2, y, row0);
    }
}